// Round 2
// baseline (425.723 us; speedup 1.0000x reference)
//
#include <hip/hip_runtime.h>

// QMN B=32,T=60,D=128. Round 13 (resubmit; prior run = infra container failure).
//  - k_meas: V staged in LDS (35KB -> 3 blk/CU vs 70KB/2), C streamed from
//    global inside the MFMA loop (loads interleave with compute instead of a
//    barrier-locked 8B staging burst), stage-2 diag moved from MFMA+atomics to
//    VALU dots on the fp32 accumulators (+shfl reduce), h-pair XCD swizzle so
//    the sibling block's C read is an L2 hit.
//  - lds_load/store_mat widened 8B -> 16B; k_prefix widened to 16B/lane.
// Everything else = r12.

#define DB 32
#define DT 60
#define DD 128
#define BT (DB*DT)
#define SP 136

typedef unsigned short ushort_t;
typedef __attribute__((ext_vector_type(8))) __bf16 bf16x8;
typedef __attribute__((ext_vector_type(8))) unsigned short ushort8_t;
typedef __attribute__((ext_vector_type(4))) float  float4v;

__device__ __forceinline__ float bf2f(ushort_t u){
  union { unsigned int i; float f; } x; x.i = ((unsigned int)u) << 16; return x.f;
}
__device__ __forceinline__ ushort_t f2bf(float f){
  union { float f; unsigned int i; } x; x.f = f;
  unsigned int lsb = (x.i >> 16) & 1u;
  return (ushort_t)((x.i + 0x7FFFu + lsb) >> 16);
}
__device__ __forceinline__ unsigned int f2bfpk(float a, float b){
#if defined(__gfx950__) && __has_builtin(__builtin_amdgcn_cvt_pk_bf16_f32)
  auto v = __builtin_amdgcn_cvt_pk_bf16_f32(a, b);
  unsigned int r; __builtin_memcpy(&r, &v, 4); return r;
#else
  return (unsigned int)f2bf(a) | ((unsigned int)f2bf(b) << 16);
#endif
}
__device__ __forceinline__ void split2(float v, ushort_t& h, ushort_t& l){
  h = f2bf(v); l = f2bf(v - bf2f(h));
}

// D[m][n] = sum_k A[m][k]*B[n][k]
template<int RT, int CT, bool ALO, bool BLO>
__device__ __forceinline__ void gemm_t(const ushort_t* Ah, const ushort_t* Al,
                                       const ushort_t* Bh, const ushort_t* Bl,
                                       float4v* acc, int row0, int col0, int gma, int q)
{
  for (int ks = 0; ks < 4; ks++){
    int ko = ks*32 + q*8;
    bf16x8 aF[RT], aL[RT], bF[CT], bL[CT];
    #pragma unroll
    for (int R = 0; R < RT; R++){
      int row = row0 + 16*R + gma;
      aF[R] = *(const bf16x8*)&Ah[row*SP + ko];
      if (ALO) aL[R] = *(const bf16x8*)&Al[row*SP + ko];
    }
    #pragma unroll
    for (int C = 0; C < CT; C++){
      int row = col0 + 16*C + gma;
      bF[C] = *(const bf16x8*)&Bh[row*SP + ko];
      if (BLO) bL[C] = *(const bf16x8*)&Bl[row*SP + ko];
    }
    #pragma unroll
    for (int R = 0; R < RT; R++)
      #pragma unroll
      for (int C = 0; C < CT; C++){
        float4v c = acc[R*CT+C];
        c = __builtin_amdgcn_mfma_f32_16x16x32_bf16(aF[R], bF[C], c, 0, 0, 0);
        if (BLO) c = __builtin_amdgcn_mfma_f32_16x16x32_bf16(aF[R], bL[C], c, 0, 0, 0);
        if (ALO) c = __builtin_amdgcn_mfma_f32_16x16x32_bf16(aL[R], bF[C], c, 0, 0, 0);
        acc[R*CT+C] = c;
      }
  }
}

// transposed store computed(m,n) -> dst[n*stride + m]
template<int RT, int CT>
__device__ __forceinline__ void emit_t(const float4v* acc, ushort_t* dst, int stride,
                                       int row0, int col0, int gma, int q){
  #pragma unroll
  for (int R = 0; R < RT; R++)
    #pragma unroll
    for (int C = 0; C < CT; C++){
      int c = col0 + 16*C + gma, r0 = row0 + 16*R + 4*q;
      uint2 o;
      o.x = f2bfpk(acc[R*CT+C][0], acc[R*CT+C][1]);
      o.y = f2bfpk(acc[R*CT+C][2], acc[R*CT+C][3]);
      *(uint2*)&dst[(size_t)c*stride + r0] = o;
    }
}
template<int RT, int CT>
__device__ __forceinline__ void emit_split_t(const float4v* acc, ushort_t* dh, ushort_t* dl, int stride,
                                             int row0, int col0, int gma, int q){
  #pragma unroll
  for (int R = 0; R < RT; R++)
    #pragma unroll
    for (int C = 0; C < CT; C++){
      int c = col0 + 16*C + gma, r0 = row0 + 16*R + 4*q;
      ushort4 hh, ll;
      split2(acc[R*CT+C][0], hh.x, ll.x); split2(acc[R*CT+C][1], hh.y, ll.y);
      split2(acc[R*CT+C][2], hh.z, ll.z); split2(acc[R*CT+C][3], hh.w, ll.w);
      *(ushort4*)&dh[(size_t)c*stride + r0] = hh;
      *(ushort4*)&dl[(size_t)c*stride + r0] = ll;
    }
}
template<int NT>
__device__ __forceinline__ void lds_load_mat(ushort_t* dst, const ushort_t* src, int tid){
  for (int i = tid*8; i < 16384; i += NT*8){
    int r = i >> 7, k = i & 127;
    *(ushort8_t*)&dst[r*SP + k] = *(const ushort8_t*)&src[i];
  }
}
template<int NT>
__device__ __forceinline__ void lds_store_mat(ushort_t* dst, const ushort_t* src, int tid){
  for (int i = tid*8; i < 16384; i += NT*8){
    int r = i >> 7, k = i & 127;
    *(ushort8_t*)&dst[i] = *(const ushort8_t*)&src[r*SP + k];
  }
}

// ---- small: prepU | normv | initG ----
__global__ void k_small(const float* Ux, const float* Uh, const float* kr, const float* ki,
                        ushort_t* UxTh, ushort_t* UxTl, float* Vr, float* Vi,
                        ushort_t* PpH, ushort_t* PpL, ushort_t* PTh, ushort_t* PTl){
  int blk = blockIdx.x, d = threadIdx.x;
  if (blk < 128){
    int i = blk;
    float v = Ux[i*DD + d];
    ushort_t h, l; split2(v, h, l);
    UxTh[d*DD + i] = h; UxTl[d*DD + i] = l;
  } else if (blk < 256){
    __shared__ float red[DD];
    int k = blk - 128;
    float r = kr[k*DD+d], im = ki[k*DD+d];
    red[d] = r*r + im*im;
    __syncthreads();
    for (int s = 64; s > 0; s >>= 1){ if (d < s) red[d] += red[d+s]; __syncthreads(); }
    float nrm = fmaxf(sqrtf(red[0]), 1e-12f);
    Vr[k*DD+d] = r/nrm; Vi[k*DD+d] = im/nrm;
  } else {
    int i = blk - 256;
    float v = Uh[i*DD + d];
    ushort_t h, l; split2(v, h, l);
    PpH[i*DD + d] = h;  PpL[i*DD + d] = l;
    PTh[d*DD + i] = h;  PTl[d*DD + i] = l;
  }
}

// ---- pow2step ----
__global__ __launch_bounds__(512,1) void k_pow2step(ushort_t* PpH, ushort_t* PpL,
                                                    ushort_t* PTh, ushort_t* PTl, int s){
  __shared__ ushort_t Ah[128*SP], Al[128*SP], Bh[128*SP], Bl[128*SP];
  int which = blockIdx.x;
  size_t src = (size_t)(s-1)*16384, dst = (size_t)s*16384;
  int tid = threadIdx.x;
  int w = tid >> 6, lane = tid & 63, gma = lane & 15, q = lane >> 4;
  int row0 = 32*(w >> 1), col0 = 64*(w & 1);
  if (which == 0){
    lds_load_mat<512>(Ah, PTh + src, tid); lds_load_mat<512>(Al, PTl + src, tid);
    lds_load_mat<512>(Bh, PpH + src, tid); lds_load_mat<512>(Bl, PpL + src, tid);
  } else {
    lds_load_mat<512>(Ah, PpH + src, tid); lds_load_mat<512>(Al, PpL + src, tid);
    lds_load_mat<512>(Bh, PTh + src, tid); lds_load_mat<512>(Bl, PTl + src, tid);
  }
  __syncthreads();
  float4v acc[8];
  #pragma unroll
  for (int i = 0; i < 8; i++) acc[i] = (float4v){0.f,0.f,0.f,0.f};
  gemm_t<2,4,true,true>(Ah, Al, Bh, Bl, acc, row0, col0, gma, q);
  if (which == 0) emit_split_t<2,4>(acc, PpH + dst, PpL + dst, 128, row0, col0, gma, q);
  else            emit_split_t<2,4>(acc, PTh + dst, PTl + dst, 128, row0, col0, gma, q);
}

// ---- gchain ----
__global__ __launch_bounds__(512,1) void k_gchain(const ushort_t* PpH, const ushort_t* PpL,
                                                  const ushort_t* PTh, const ushort_t* PTl,
                                                  ushort_t* GTh, ushort_t* GTl){
  __shared__ ushort_t Ah[128*SP], Al[128*SP], Bh[128*SP], Bl[128*SP];
  int t = blockIdx.x;
  int tid = threadIdx.x;
  int w = tid >> 6, lane = tid & 63, gma = lane & 15, q = lane >> 4;
  int row0 = 32*(w >> 1), col0 = 64*(w & 1);
  size_t gslot = (size_t)t * 16384;
  if (t == 0){
    for (int i = tid*4; i < 16384; i += 2048){
      int r = i >> 7, k = i & 127;
      ushort4 zz; zz.x = zz.y = zz.z = zz.w = 0;
      *(ushort4*)&GTl[gslot + i] = zz;
      ushort4 oh;
      oh.x = (r == (k+0)) ? (ushort_t)0x3F80 : (ushort_t)0;
      oh.y = (r == (k+1)) ? (ushort_t)0x3F80 : (ushort_t)0;
      oh.z = (r == (k+2)) ? (ushort_t)0x3F80 : (ushort_t)0;
      oh.w = (r == (k+3)) ? (ushort_t)0x3F80 : (ushort_t)0;
      *(ushort4*)&GTh[gslot + i] = oh;
    }
    return;
  }
  int b0 = __ffs(t) - 1;
  int rem = t & ~(1 << b0);
  if (rem == 0){
    size_t ps = (size_t)b0 * 16384;
    for (int i = tid*4; i < 16384; i += 2048){
      *(ushort4*)&GTh[gslot + i] = *(const ushort4*)&PTh[ps + i];
      *(ushort4*)&GTl[gslot + i] = *(const ushort4*)&PTl[ps + i];
    }
    return;
  }
  lds_load_mat<512>(Ah, PpH + (size_t)b0*16384, tid);
  lds_load_mat<512>(Al, PpL + (size_t)b0*16384, tid);
  while (rem){
    int k = __ffs(rem) - 1;
    rem &= ~(1 << k);
    lds_load_mat<512>(Bh, PTh + (size_t)k*16384, tid);
    lds_load_mat<512>(Bl, PTl + (size_t)k*16384, tid);
    __syncthreads();
    float4v acc[8];
    #pragma unroll
    for (int i = 0; i < 8; i++) acc[i] = (float4v){0.f,0.f,0.f,0.f};
    if (rem){
      gemm_t<2,4,true,true>(Bh, Bl, Ah, Al, acc, row0, col0, gma, q);
      __syncthreads();
      emit_split_t<2,4>(acc, Ah, Al, SP, row0, col0, gma, q);
      __syncthreads();
    } else {
      gemm_t<2,4,true,true>(Ah, Al, Bh, Bl, acc, row0, col0, gma, q);
      emit_split_t<2,4>(acc, GTh + gslot, GTl + gslot, 128, row0, col0, gma, q);
    }
  }
}

// ---- precompMW ----
__global__ __launch_bounds__(256,1) void k_precompMW(const ushort_t* GTh, const ushort_t* GTl,
                                                     const ushort_t* UxTh, const ushort_t* UxTl,
                                                     const float* Vr, const float* Vi,
                                                     ushort_t* Mh, ushort_t* Wh){
  __shared__ ushort_t Bh[128*SP], Bl[128*SP], Ah[128*SP], Al[128*SP];
  int blk = blockIdx.x;
  int tid = threadIdx.x;
  int w = tid >> 6, lane = tid & 63, gma = lane & 15, q = lane >> 4;
  int row0 = 64*(w >> 1), col0 = 64*(w & 1);
  if (blk < 60){
    int t = blk;
    lds_load_mat<256>(Bh, GTh + (size_t)t*16384, tid);
    lds_load_mat<256>(Bl, GTl + (size_t)t*16384, tid);
    lds_load_mat<256>(Ah, UxTh, tid);
    lds_load_mat<256>(Al, UxTl, tid);
    __syncthreads();
    float4v acc[16];
    #pragma unroll
    for (int i = 0; i < 16; i++) acc[i] = (float4v){0.f,0.f,0.f,0.f};
    gemm_t<4,4,true,true>(Ah, Al, Bh, Bl, acc, row0, col0, gma, q);
    __syncthreads();
    emit_split_t<4,4>(acc, Ah, Al, SP, row0, col0, gma, q);
    __syncthreads();
    #pragma unroll
    for (int i = 0; i < 16; i++) acc[i] = (float4v){0.f,0.f,0.f,0.f};
    gemm_t<4,4,true,true>(Bh, Bl, Ah, Al, acc, row0, col0, gma, q);
    #pragma unroll
    for (int R = 0; R < 4; R++)
      #pragma unroll
      for (int C = 0; C < 4; C++){
        int c = col0 + 16*C + gma, r0 = row0 + 16*R + 4*q;
        uint2 o;
        o.x = f2bfpk(acc[R*4+C][0], acc[R*4+C][1]);
        o.y = f2bfpk(acc[R*4+C][2], acc[R*4+C][3]);
        *(uint2*)&Mh[(size_t)t*16384 + c*128 + r0] = o;
      }
  } else {
    int bx = blk - 60;
    int t = bx >> 1, which = bx & 1;
    lds_load_mat<256>(Ah, GTh + (size_t)t*16384, tid);
    lds_load_mat<256>(Al, GTl + (size_t)t*16384, tid);
    const float* V = which ? Vi : Vr;
    for (int i = tid; i < 16384; i += 256){
      int r = i >> 7, k = i & 127;
      ushort_t h, l; split2(V[i], h, l);
      Bh[r*SP + k] = h; Bl[r*SP + k] = l;
    }
    __syncthreads();
    float4v acc[16];
    #pragma unroll
    for (int i = 0; i < 16; i++) acc[i] = (float4v){0.f,0.f,0.f,0.f};
    gemm_t<4,4,true,true>(Ah, Al, Bh, Bl, acc, row0, col0, gma, q);
    #pragma unroll
    for (int R = 0; R < 4; R++)
      #pragma unroll
      for (int C = 0; C < 4; C++){
        int c = col0 + 16*C + gma, r0 = row0 + 16*R + 4*q;
        uint2 o;
        o.x = f2bfpk(acc[R*4+C][0], acc[R*4+C][1]);
        o.y = f2bfpk(acc[R*4+C][2], acc[R*4+C][3]);
        *(uint2*)&Wh[(size_t)bx*16384 + c*128 + r0] = o;
      }
  }
}

// ---- prep (fused qtrans) ----
__global__ __launch_bounds__(128) void k_prep(
    const float* x0, const float* x1, const float* x2, const float* smask,
    const float* Wp0, const float* bp0, const float* Wp1, const float* bp1,
    const float* Wp2, const float* bp2, const float* freq, const float* phem,
    const float* Ux, float* Q, float* Wgt)
{
  __shared__ float xs[768+74+35];
  __shared__ float red[DD];
  __shared__ float nrm3[3];
  __shared__ float ps[6][DD];
  int bt = blockIdx.x; int t = bt % DT;
  int d = threadIdx.x;
  const float* r0 = x0 + (size_t)bt*768;
  for (int k = d; k < 768; k += DD) xs[k] = r0[k];
  const float* r1 = x1 + (size_t)bt*74;
  if (d < 74) xs[768+d] = r1[d];
  const float* r2 = x2 + (size_t)bt*35;
  if (d < 35) xs[768+74+d] = r2[d];
  __syncthreads();
  float rep[3];
  { float acc = bp0[d]; for (int k = 0; k < 768; k++) acc += xs[k]*Wp0[k*DD+d]; rep[0] = fmaxf(acc, 0.f); }
  { float acc = bp1[d]; for (int k = 0; k < 74; k++) acc += xs[768+k]*Wp1[k*DD+d]; rep[1] = fmaxf(acc, 0.f); }
  { float acc = bp2[d]; for (int k = 0; k < 35; k++) acc += xs[768+74+k]*Wp2[k*DD+d]; rep[2] = fmaxf(acc, 0.f); }
  for (int m = 0; m < 3; m++){
    red[d] = rep[m]*rep[m];
    __syncthreads();
    for (int s = 64; s > 0; s >>= 1){ if (d < s) red[d] += red[d+s]; __syncthreads(); }
    if (d == 0) nrm3[m] = sqrtf(red[0]);
    __syncthreads();
  }
  float n0 = nrm3[0], n1 = nrm3[1], n2 = nrm3[2];
  float mx = fmaxf(n0, fmaxf(n1, n2));
  float e0 = expf(n0-mx), e1 = expf(n1-mx), e2 = expf(n2-mx);
  float einv = 1.f/(e0+e1+e2);
  if (d < 3) Wgt[bt*3+d] = (d==0?e0:(d==1?e1:e2))*einv;
  float s0 = smask[bt*2], s1 = smask[bt*2+1];
  int id = (s1 > s0) ? 1 : 0;
  float ph = (float)t * freq[id*DD+d] + phem[id*DD+d];
  float cp = cosf(ph), sp = sinf(ph);
  for (int m = 0; m < 3; m++){
    float a = rep[m] / fmaxf(nrm3[m], 1e-12f);
    ps[m][d]   = a*cp;
    ps[3+m][d] = a*sp;
  }
  __syncthreads();
  float qv[6] = {0.f,0.f,0.f,0.f,0.f,0.f};
  const float* uxr = Ux + (size_t)d*DD;
  for (int p = 0; p < DD; p++){
    float u = uxr[p];
    #pragma unroll
    for (int j = 0; j < 6; j++) qv[j] += u * ps[j][p];
  }
  #pragma unroll
  for (int j = 0; j < 6; j++)
    Q[((size_t)(j*BT) + bt)*DD + d] = qv[j];
}

// ---- vtrans: per t, A'[j,b] = G_t^T q_{j,b} for all 192 vectors ----
__global__ __launch_bounds__(512,1) void k_vtrans(const ushort_t* GTh, const float* Q, ushort_t* At){
  __shared__ ushort_t Ah[128*SP];
  __shared__ ushort_t Bs[192*SP];
  int t = blockIdx.x;
  int tid = threadIdx.x;
  int w = tid >> 6, lane = tid & 63, gma = lane & 15, q = lane >> 4;
  int row0 = (w & 3)*32, col0 = (w >> 2)*96;
  lds_load_mat<512>(Ah, GTh + (size_t)t*16384, tid);
  for (int i = tid*4; i < 192*128; i += 2048){
    int m = i >> 7, k = i & 127;
    int j = m >> 5, b = m & 31;
    const float* src = &Q[((size_t)(j*BT) + b*DT + t)*DD + k];
    uint2 o; o.x = f2bfpk(src[0], src[1]); o.y = f2bfpk(src[2], src[3]);
    *(uint2*)&Bs[m*SP + k] = o;
  }
  __syncthreads();
  float4v acc[12];
  #pragma unroll
  for (int i = 0; i < 12; i++) acc[i] = (float4v){0.f,0.f,0.f,0.f};
  gemm_t<2,6,false,false>(Ah, Ah, Bs, Bs, acc, row0, col0, gma, q);
  emit_t<2,6>(acc, At + (size_t)t*24576, 128, row0, col0, gma, q);
}

// ---- zbuild: fused rank-6 Y build + lambda-prefix; writes Z into S ----
__global__ __launch_bounds__(256) void k_zbuild(ushort_t* S, const ushort_t* At,
                                                const float* Wgt, const float* lamp){
  __shared__ ushort_t As[6*DD];
  __shared__ float wl[3];
  int blk = blockIdx.x;            // 512 = 32 b x 16 slabs
  int b = blk >> 4, slab = blk & 15;
  int tid = threadIdx.x;
  int r = slab*8 + (tid >> 5);
  int c0 = (tid & 31)*4;
  float lam = lamp[0];
  float z0=0.f, z1=0.f, z2=0.f, z3=0.f;
  size_t off = (size_t)slab*1024 + tid*4;
  for (int t = 0; t < DT; t++){
    __syncthreads();
    if (tid < 192){
      int i = tid*4;
      int jj = i >> 7, n = i & 127;
      *(ushort4*)&As[i] = *(const ushort4*)&At[(size_t)t*24576 + (jj*32 + b)*128 + n];
    }
    if (tid < 3) wl[tid] = Wgt[(b*DT + t)*3 + tid];
    __syncthreads();
    float ar[6];
    #pragma unroll
    for (int jj = 0; jj < 6; jj++) ar[jj] = bf2f(As[jj*128 + r]);
    float cb[6];
    cb[0] = wl[0]*(ar[0]+ar[3]); cb[1] = wl[1]*(ar[1]+ar[4]); cb[2] = wl[2]*(ar[2]+ar[5]);
    cb[3] = wl[0]*(ar[3]-ar[0]); cb[4] = wl[1]*(ar[4]-ar[1]); cb[5] = wl[2]*(ar[5]-ar[2]);
    float y0=0.f, y1=0.f, y2=0.f, y3=0.f;
    #pragma unroll
    for (int jj = 0; jj < 6; jj++){
      ushort4 a4 = *(const ushort4*)&As[jj*128 + c0];
      float w_ = cb[jj];
      y0 += w_*bf2f(a4.x); y1 += w_*bf2f(a4.y);
      y2 += w_*bf2f(a4.z); y3 += w_*bf2f(a4.w);
    }
    z0 = lam*z0 + y0; z1 = lam*z1 + y1;
    z2 = lam*z2 + y2; z3 = lam*z3 + y3;
    uint2 o; o.x = f2bfpk(z0, z1); o.y = f2bfpk(z2, z3);
    *(uint2*)&S[((size_t)(t*32 + b))*16384 + off] = o;
  }
}

// ---- conjmid (512 thr, per (t,b)): S <- (1-l) M S M^T + c_t I ----
__global__ __launch_bounds__(512,4) void k_conjmid(ushort_t* S, const ushort_t* Mh,
                                                   const float* lamp){
  __shared__ ushort_t Bh[128*SP], Zs[128*SP];
  int blk = blockIdx.x;
  int t = blk >> 5;
  size_t slot = (size_t)blk * 16384;
  int tid = threadIdx.x;
  int w = tid >> 6, lane = tid & 63, gma = lane & 15, q = lane >> 4;
  int row0 = 32*(w >> 1), col0 = 64*(w & 1);
  lds_load_mat<512>(Bh, Mh + (size_t)t*16384, tid);
  lds_load_mat<512>(Zs, S + slot, tid);
  __syncthreads();
  float lam = lamp[0];
  float oml = 1.f - lam;
  float ct = powf(lam, (float)(t+1)) / 128.f;
  float4v acc[8];
  #pragma unroll
  for (int i = 0; i < 8; i++) acc[i] = (float4v){0.f,0.f,0.f,0.f};
  gemm_t<2,4,false,false>(Zs, Zs, Bh, Bh, acc, row0, col0, gma, q);
  __syncthreads();
  emit_t<2,4>(acc, Zs, SP, row0, col0, gma, q);
  __syncthreads();
  #pragma unroll
  for (int i = 0; i < 8; i++) acc[i] = (float4v){0.f,0.f,0.f,0.f};
  gemm_t<2,4,false,false>(Zs, Zs, Bh, Bh, acc, row0, col0, gma, q);
  __syncthreads();
  #pragma unroll
  for (int R = 0; R < 2; R++)
    #pragma unroll
    for (int C = 0; C < 4; C++){
      int c = col0 + 16*C + gma, r0 = row0 + 16*R + 4*q;
      float v0 = oml*acc[R*4+C][0] + ((c == r0+0) ? ct : 0.f);
      float v1 = oml*acc[R*4+C][1] + ((c == r0+1) ? ct : 0.f);
      float v2 = oml*acc[R*4+C][2] + ((c == r0+2) ? ct : 0.f);
      float v3 = oml*acc[R*4+C][3] + ((c == r0+3) ? ct : 0.f);
      uint2 o; o.x = f2bfpk(v0, v1); o.y = f2bfpk(v2, v3);
      *(uint2*)&Zs[(size_t)c*SP + r0] = o;
    }
  __syncthreads();
  lds_store_mat<512>(S + slot, Zs, tid);
}

// ---- prefix: Z_t = lam*Z_{t-1} + Y_t (32 chains), 16B/lane ----
__global__ __launch_bounds__(128) void k_prefix(ushort_t* S, const float* lamp){
  int blk = blockIdx.x;            // 512 = 32 chains x 16 slabs
  int chain = blk >> 4, slab = blk & 15;
  int tid = threadIdx.x;
  size_t off = (size_t)slab*1024 + tid*8;
  float lam = lamp[0];
  float a[8];
  #pragma unroll
  for (int i = 0; i < 8; i++) a[i] = 0.f;
  size_t addr = (size_t)chain*16384 + off;
  const size_t step = (size_t)32*16384;
  ushort8_t nxt = *(const ushort8_t*)&S[addr];
  for (int t = 0; t < DT; t++){
    ushort8_t u = nxt;
    if (t < DT-1) nxt = *(const ushort8_t*)&S[addr + step];
    #pragma unroll
    for (int i = 0; i < 8; i++) a[i] = lam*a[i] + bf2f(u[i]);
    uint4 o;
    o.x = f2bfpk(a[0], a[1]); o.y = f2bfpk(a[2], a[3]);
    o.z = f2bfpk(a[4], a[5]); o.w = f2bfpk(a[6], a[7]);
    *(uint4*)&S[addr] = o;
    addr += step;
  }
}

// ---- meas v2 (512 thr, per (tb,h)): V in LDS (35KB), C streamed from global
// inside the MFMA loop, diag via VALU dots on fp32 acc + shfl reduce.
// D[a][m] = sum_n V[a,n]*C[m,n] = (C v_a)[m]
// p_k = sum_m D[k][m]*(vr_k[m]+vi_k[m]) + D[64+k][m]*(vi_k[m]-vr_k[m])
//     = vr'Cvr + vi'Cvi - vr'Cvi + vi'Cvr   (matches old stage-2 semantics)
__global__ __launch_bounds__(512,6) void k_meas(const ushort_t* S, const ushort_t* Wh,
                                                const float* lamp, float* Probs){
  __shared__ ushort_t Vs[128*SP];
  __shared__ float Pd[64];
  int raw = blockIdx.x;
  // XCD-pair swizzle: raw and raw+8 are the (h=0,h=1) pair of the same tb ->
  // same XCD under round-robin -> sibling's C read hits L2.
  int tb = (raw & 7) | ((raw >> 4) << 3);
  int h  = (raw >> 3) & 1;
  int t = tb >> 5;
  int tid = threadIdx.x;
  int w = tid >> 6, lane = tid & 63, gma = lane & 15, q = lane >> 4;
  int row0 = 16*(w >> 1);          // a-tile base: R=0 -> row0, R=1 -> row0+64
  int col0 = 64*(w & 1);           // m base
  size_t slot = (size_t)tb * 16384;
  size_t wbase = (size_t)(t*2) * 16384;
  // stage V: rows 0..63 = Wr[64h+r], rows 64..127 = Wi[64h+r]; 16B loads
  for (int i = tid*8; i < 16384; i += 4096){
    int r = i >> 7, k = i & 127;
    size_t gsrc = wbase + ((r < 64) ? 0 : 16384) + (size_t)(64*h + (r & 63))*128 + k;
    *(ushort8_t*)&Vs[r*SP + k] = *(const ushort8_t*)&Wh[gsrc];
  }
  if (tid < 64) Pd[tid] = 0.f;
  __syncthreads();
  const ushort_t* Sg = S + slot;
  float4v acc[8];
  #pragma unroll
  for (int i = 0; i < 8; i++) acc[i] = (float4v){0.f,0.f,0.f,0.f};
  #pragma unroll
  for (int ks = 0; ks < 4; ks++){
    int ko = ks*32 + q*8;
    bf16x8 aF0 = *(const bf16x8*)&Vs[(row0 + gma)*SP + ko];
    bf16x8 aF1 = *(const bf16x8*)&Vs[(row0 + 64 + gma)*SP + ko];
    bf16x8 bF[4];
    #pragma unroll
    for (int C = 0; C < 4; C++)
      bF[C] = *(const bf16x8*)&Sg[(size_t)(col0 + 16*C + gma)*128 + ko];
    #pragma unroll
    for (int C = 0; C < 4; C++){
      acc[C]   = __builtin_amdgcn_mfma_f32_16x16x32_bf16(aF0, bF[C], acc[C],   0, 0, 0);
      acc[4+C] = __builtin_amdgcn_mfma_f32_16x16x32_bf16(aF1, bF[C], acc[4+C], 0, 0, 0);
    }
  }
  // stage 2: k = row0 + 4q + j; sum over this lane's 4 m per C, then over gma.
  #pragma unroll
  for (int j = 0; j < 4; j++){
    int kr = row0 + 4*q + j;
    float s = 0.f;
    #pragma unroll
    for (int C = 0; C < 4; C++){
      int m = col0 + 16*C + gma;
      float w0 = bf2f(Vs[kr*SP + m]);          // vr_k[m]
      float w1 = bf2f(Vs[(kr + 64)*SP + m]);   // vi_k[m]
      s += acc[C][j]*(w0 + w1) + acc[4+C][j]*(w1 - w0);
    }
    #pragma unroll
    for (int off = 1; off < 16; off <<= 1)
      s += __shfl_xor(s, off, 64);
    if (gma == 0) atomicAdd(&Pd[kr], s);
  }
  __syncthreads();
  if (tid < 64){
    float lam = lamp[0];
    float ct = powf(lam, (float)(t+1)) / 128.f;
    Probs[(size_t)tb*DD + 64*h + tid] = (1.f - lam)*Pd[tid] + ct;
  }
}

// ---- head ----
__global__ __launch_bounds__(64) void k_head(const float* Probs, const float* W1, const float* b1,
                        const float* W2, const float* b2, float* out)
{
  __shared__ float ps[DD];
  __shared__ float hid[64];
  __shared__ float ov[4];
  int tb = blockIdx.x;
  int tid = threadIdx.x;
  ps[tid] = Probs[(size_t)tb*DD + tid];
  ps[tid+64] = Probs[(size_t)tb*DD + 64 + tid];
  __syncthreads();
  float acc = b1[tid];
  for (int dd = 0; dd < DD; dd++) acc += ps[dd]*W1[dd*64 + tid];
  hid[tid] = fmaxf(acc, 0.f);
  __syncthreads();
  if (tid < 4){
    float o = b2[tid];
    for (int j = 0; j < 64; j++) o += hid[j]*W2[j*4 + tid];
    ov[tid] = tanhf(o);
  }
  __syncthreads();
  if (tid == 0){
    float m = fmaxf(fmaxf(ov[0],ov[1]), fmaxf(ov[2],ov[3]));
    float lse = logf(expf(ov[0]-m)+expf(ov[1]-m)+expf(ov[2]-m)+expf(ov[3]-m));
    int t = tb >> 5, b = tb & 31;
    float* o = out + ((size_t)(b*DT + t))*4;
    o[0] = ov[0]-m-lse; o[1] = ov[1]-m-lse;
    o[2] = ov[2]-m-lse; o[3] = ov[3]-m-lse;
  }
}

extern "C" void kernel_launch(void* const* d_in, const int* in_sizes, int n_in,
                              void* d_out, int out_size, void* d_ws, size_t ws_size,
                              hipStream_t stream)
{
  const float* x0    = (const float*)d_in[0];
  const float* x1    = (const float*)d_in[1];
  const float* x2    = (const float*)d_in[2];
  const float* smask = (const float*)d_in[3];
  const float* Wp0   = (const float*)d_in[4];
  const float* bp0   = (const float*)d_in[5];
  const float* Wp1   = (const float*)d_in[6];
  const float* bp1   = (const float*)d_in[7];
  const float* Wp2   = (const float*)d_in[8];
  const float* bp2   = (const float*)d_in[9];
  const float* freq  = (const float*)d_in[10];
  const float* phem  = (const float*)d_in[11];
  const float* Ux    = (const float*)d_in[12];
  const float* Uh    = (const float*)d_in[13];
  const float* lamp  = (const float*)d_in[14];
  const float* kr    = (const float*)d_in[15];
  const float* ki    = (const float*)d_in[16];
  const float* W1    = (const float*)d_in[17];
  const float* b1    = (const float*)d_in[18];
  const float* W2    = (const float*)d_in[19];
  const float* b2    = (const float*)d_in[20];

  char* ws = (char*)d_ws;
  auto alignup = [](size_t x){ return (x + 255) & ~(size_t)255; };
  size_t off = 0;
  ushort_t* S   = (ushort_t*)(ws + off); off = alignup(off + (size_t)1920*16384*sizeof(ushort_t));
  float* Qbuf   = (float*)(ws + off);    off = alignup(off + (size_t)6*BT*DD*sizeof(float));
  float* Wgt    = (float*)(ws + off);    off = alignup(off + (size_t)BT*3*sizeof(float));
  float* Vr     = (float*)(ws + off);    off = alignup(off + (size_t)DD*DD*sizeof(float));
  float* Vi     = (float*)(ws + off);    off = alignup(off + (size_t)DD*DD*sizeof(float));
  ushort_t* UxTh = (ushort_t*)(ws + off); off = alignup(off + (size_t)DD*DD*sizeof(ushort_t));
  ushort_t* UxTl = (ushort_t*)(ws + off); off = alignup(off + (size_t)DD*DD*sizeof(ushort_t));
  float* Probs  = (float*)(ws + off);    off = alignup(off + (size_t)BT*DD*sizeof(float));
  ushort_t* PpH = (ushort_t*)(ws + off); off = alignup(off + (size_t)6*16384*sizeof(ushort_t));
  ushort_t* PpL = (ushort_t*)(ws + off); off = alignup(off + (size_t)6*16384*sizeof(ushort_t));
  ushort_t* PTh = (ushort_t*)(ws + off); off = alignup(off + (size_t)6*16384*sizeof(ushort_t));
  ushort_t* PTl = (ushort_t*)(ws + off); off = alignup(off + (size_t)6*16384*sizeof(ushort_t));
  ushort_t* Mh  = (ushort_t*)(ws + off); off = alignup(off + (size_t)60*16384*sizeof(ushort_t));
  ushort_t* Wmh = (ushort_t*)(ws + off); off = alignup(off + (size_t)120*16384*sizeof(ushort_t));
  ushort_t* GTh = (ushort_t*)(ws + off); off = alignup(off + (size_t)60*16384*sizeof(ushort_t));
  ushort_t* GTl = (ushort_t*)(ws + off); off = alignup(off + (size_t)60*16384*sizeof(ushort_t));
  ushort_t* At  = (ushort_t*)(ws + off); off = alignup(off + (size_t)60*24576*sizeof(ushort_t));
  (void)ws_size; (void)in_sizes; (void)n_in; (void)out_size;

  k_small<<<384, 128, 0, stream>>>(Ux, Uh, kr, ki, UxTh, UxTl, Vr, Vi, PpH, PpL, PTh, PTl);
  k_prep<<<BT, 128, 0, stream>>>(x0, x1, x2, smask, Wp0, bp0, Wp1, bp1, Wp2, bp2, freq, phem, Ux, Qbuf, Wgt);
  for (int s = 1; s <= 5; s++)
    k_pow2step<<<2, 512, 0, stream>>>(PpH, PpL, PTh, PTl, s);
  k_gchain<<<60, 512, 0, stream>>>(PpH, PpL, PTh, PTl, GTh, GTl);
  k_precompMW<<<180, 256, 0, stream>>>(GTh, GTl, UxTh, UxTl, Vr, Vi, Mh, Wmh);
  k_vtrans<<<60, 512, 0, stream>>>(GTh, Qbuf, At);
  k_zbuild<<<512, 256, 0, stream>>>(S, At, Wgt, lamp);
  k_conjmid<<<1920, 512, 0, stream>>>(S, Mh, lamp);
  k_prefix<<<512, 128, 0, stream>>>(S, lamp);
  k_meas<<<3840, 512, 0, stream>>>(S, Wmh, lamp, Probs);
  k_head<<<BT, 64, 0, stream>>>(Probs, W1, b1, W2, b2, (float*)d_out);
}

// Round 3
// 390.585 us; speedup vs baseline: 1.0900x; 1.0900x over previous
//
#include <hip/hip_runtime.h>

// QMN B=32,T=60,D=128. Round 14: recombine proven pieces.
//  - k_meas v4: r12 staged-LDS structure (contiguous 16B bursts, 1215 GB/s
//    proven) + r13 XCD h-pair swizzle (FETCH -33% proven) + r13 VALU stage-2
//    (no 2nd MFMA stage / no mid emit+barrier) + issue-early reg staging.
//  - k_pow2all: 5 serial 2-block launches -> 1 single-block kernel, all 4
//    mats resident in 139KB LDS, steps s=1..5 in-LDS (global spill per step
//    for gchain).
//  - k_prefix: depth-4 register prefetch (static indices).
//  - k_conjmid: issue-early combined staging (loads first, then ds_writes).
// Everything else = r13.

#define DB 32
#define DT 60
#define DD 128
#define BT (DB*DT)
#define SP 136

typedef unsigned short ushort_t;
typedef __attribute__((ext_vector_type(8))) __bf16 bf16x8;
typedef __attribute__((ext_vector_type(8))) unsigned short ushort8_t;
typedef __attribute__((ext_vector_type(4))) float  float4v;

__device__ __forceinline__ float bf2f(ushort_t u){
  union { unsigned int i; float f; } x; x.i = ((unsigned int)u) << 16; return x.f;
}
__device__ __forceinline__ ushort_t f2bf(float f){
  union { float f; unsigned int i; } x; x.f = f;
  unsigned int lsb = (x.i >> 16) & 1u;
  return (ushort_t)((x.i + 0x7FFFu + lsb) >> 16);
}
__device__ __forceinline__ unsigned int f2bfpk(float a, float b){
#if defined(__gfx950__) && __has_builtin(__builtin_amdgcn_cvt_pk_bf16_f32)
  auto v = __builtin_amdgcn_cvt_pk_bf16_f32(a, b);
  unsigned int r; __builtin_memcpy(&r, &v, 4); return r;
#else
  return (unsigned int)f2bf(a) | ((unsigned int)f2bf(b) << 16);
#endif
}
__device__ __forceinline__ void split2(float v, ushort_t& h, ushort_t& l){
  h = f2bf(v); l = f2bf(v - bf2f(h));
}

// D[m][n] = sum_k A[m][k]*B[n][k]
template<int RT, int CT, bool ALO, bool BLO>
__device__ __forceinline__ void gemm_t(const ushort_t* Ah, const ushort_t* Al,
                                       const ushort_t* Bh, const ushort_t* Bl,
                                       float4v* acc, int row0, int col0, int gma, int q)
{
  for (int ks = 0; ks < 4; ks++){
    int ko = ks*32 + q*8;
    bf16x8 aF[RT], aL[RT], bF[CT], bL[CT];
    #pragma unroll
    for (int R = 0; R < RT; R++){
      int row = row0 + 16*R + gma;
      aF[R] = *(const bf16x8*)&Ah[row*SP + ko];
      if (ALO) aL[R] = *(const bf16x8*)&Al[row*SP + ko];
    }
    #pragma unroll
    for (int C = 0; C < CT; C++){
      int row = col0 + 16*C + gma;
      bF[C] = *(const bf16x8*)&Bh[row*SP + ko];
      if (BLO) bL[C] = *(const bf16x8*)&Bl[row*SP + ko];
    }
    #pragma unroll
    for (int R = 0; R < RT; R++)
      #pragma unroll
      for (int C = 0; C < CT; C++){
        float4v c = acc[R*CT+C];
        c = __builtin_amdgcn_mfma_f32_16x16x32_bf16(aF[R], bF[C], c, 0, 0, 0);
        if (BLO) c = __builtin_amdgcn_mfma_f32_16x16x32_bf16(aF[R], bL[C], c, 0, 0, 0);
        if (ALO) c = __builtin_amdgcn_mfma_f32_16x16x32_bf16(aL[R], bF[C], c, 0, 0, 0);
        acc[R*CT+C] = c;
      }
  }
}

// transposed store computed(m,n) -> dst[n*stride + m]
template<int RT, int CT>
__device__ __forceinline__ void emit_t(const float4v* acc, ushort_t* dst, int stride,
                                       int row0, int col0, int gma, int q){
  #pragma unroll
  for (int R = 0; R < RT; R++)
    #pragma unroll
    for (int C = 0; C < CT; C++){
      int c = col0 + 16*C + gma, r0 = row0 + 16*R + 4*q;
      uint2 o;
      o.x = f2bfpk(acc[R*CT+C][0], acc[R*CT+C][1]);
      o.y = f2bfpk(acc[R*CT+C][2], acc[R*CT+C][3]);
      *(uint2*)&dst[(size_t)c*stride + r0] = o;
    }
}
template<int RT, int CT>
__device__ __forceinline__ void emit_split_t(const float4v* acc, ushort_t* dh, ushort_t* dl, int stride,
                                             int row0, int col0, int gma, int q){
  #pragma unroll
  for (int R = 0; R < RT; R++)
    #pragma unroll
    for (int C = 0; C < CT; C++){
      int c = col0 + 16*C + gma, r0 = row0 + 16*R + 4*q;
      ushort4 hh, ll;
      split2(acc[R*CT+C][0], hh.x, ll.x); split2(acc[R*CT+C][1], hh.y, ll.y);
      split2(acc[R*CT+C][2], hh.z, ll.z); split2(acc[R*CT+C][3], hh.w, ll.w);
      *(ushort4*)&dh[(size_t)c*stride + r0] = hh;
      *(ushort4*)&dl[(size_t)c*stride + r0] = ll;
    }
}
template<int NT>
__device__ __forceinline__ void lds_load_mat(ushort_t* dst, const ushort_t* src, int tid){
  for (int i = tid*8; i < 16384; i += NT*8){
    int r = i >> 7, k = i & 127;
    *(ushort8_t*)&dst[r*SP + k] = *(const ushort8_t*)&src[i];
  }
}
// issue-early pair stager: all global loads issued, then all ds_writes
template<int NT>
__device__ __forceinline__ void lds_load_mat2(ushort_t* d0, const ushort_t* s0,
                                              ushort_t* d1, const ushort_t* s1, int tid){
  constexpr int CH = 16384/(NT*8);
  ushort8_t r0[CH], r1[CH];
  #pragma unroll
  for (int c = 0; c < CH; c++) r0[c] = *(const ushort8_t*)&s0[tid*8 + c*NT*8];
  #pragma unroll
  for (int c = 0; c < CH; c++) r1[c] = *(const ushort8_t*)&s1[tid*8 + c*NT*8];
  #pragma unroll
  for (int c = 0; c < CH; c++){
    int i = tid*8 + c*NT*8; int r = i >> 7, k = i & 127;
    *(ushort8_t*)&d0[r*SP + k] = r0[c];
  }
  #pragma unroll
  for (int c = 0; c < CH; c++){
    int i = tid*8 + c*NT*8; int r = i >> 7, k = i & 127;
    *(ushort8_t*)&d1[r*SP + k] = r1[c];
  }
}
template<int NT>
__device__ __forceinline__ void lds_store_mat(ushort_t* dst, const ushort_t* src, int tid){
  for (int i = tid*8; i < 16384; i += NT*8){
    int r = i >> 7, k = i & 127;
    *(ushort8_t*)&dst[i] = *(const ushort8_t*)&src[r*SP + k];
  }
}

// ---- small: prepU | normv | initG ----
__global__ void k_small(const float* Ux, const float* Uh, const float* kr, const float* ki,
                        ushort_t* UxTh, ushort_t* UxTl, float* Vr, float* Vi,
                        ushort_t* PpH, ushort_t* PpL, ushort_t* PTh, ushort_t* PTl){
  int blk = blockIdx.x, d = threadIdx.x;
  if (blk < 128){
    int i = blk;
    float v = Ux[i*DD + d];
    ushort_t h, l; split2(v, h, l);
    UxTh[d*DD + i] = h; UxTl[d*DD + i] = l;
  } else if (blk < 256){
    __shared__ float red[DD];
    int k = blk - 128;
    float r = kr[k*DD+d], im = ki[k*DD+d];
    red[d] = r*r + im*im;
    __syncthreads();
    for (int s = 64; s > 0; s >>= 1){ if (d < s) red[d] += red[d+s]; __syncthreads(); }
    float nrm = fmaxf(sqrtf(red[0]), 1e-12f);
    Vr[k*DD+d] = r/nrm; Vi[k*DD+d] = im/nrm;
  } else {
    int i = blk - 256;
    float v = Uh[i*DD + d];
    ushort_t h, l; split2(v, h, l);
    PpH[i*DD + d] = h;  PpL[i*DD + d] = l;
    PTh[d*DD + i] = h;  PTl[d*DD + i] = l;
  }
}

// ---- pow2all: all 5 pow2 steps in one block, 4 mats resident in LDS ----
// Semantics per step s (matches old k_pow2step):
//   Pp_s = gemm(A=PT_{s-1}, B=Pp_{s-1});  PT_s = gemm(A=Pp_{s-1}, B=PT_{s-1})
__global__ __launch_bounds__(512,1) void k_pow2all(ushort_t* PpH, ushort_t* PpL,
                                                   ushort_t* PTh, ushort_t* PTl){
  __shared__ ushort_t Ah[128*SP], Al[128*SP], Bh[128*SP], Bl[128*SP]; // A=PT, B=Pp
  int tid = threadIdx.x;
  int w = tid >> 6, lane = tid & 63, gma = lane & 15, q = lane >> 4;
  int row0 = 32*(w >> 1), col0 = 64*(w & 1);
  lds_load_mat2<512>(Ah, PTh, Al, PTl, tid);
  lds_load_mat2<512>(Bh, PpH, Bl, PpL, tid);
  __syncthreads();
  for (int s = 1; s <= 5; s++){
    size_t dst = (size_t)s*16384;
    float4v accP[8], accT[8];
    #pragma unroll
    for (int i = 0; i < 8; i++){ accP[i] = (float4v){0.f,0.f,0.f,0.f}; accT[i] = (float4v){0.f,0.f,0.f,0.f}; }
    gemm_t<2,4,true,true>(Ah, Al, Bh, Bl, accP, row0, col0, gma, q); // -> Pp_s
    gemm_t<2,4,true,true>(Bh, Bl, Ah, Al, accT, row0, col0, gma, q); // -> PT_s
    __syncthreads();
    emit_split_t<2,4>(accP, Bh, Bl, SP, row0, col0, gma, q);
    emit_split_t<2,4>(accT, Ah, Al, SP, row0, col0, gma, q);
    emit_split_t<2,4>(accP, PpH + dst, PpL + dst, 128, row0, col0, gma, q);
    emit_split_t<2,4>(accT, PTh + dst, PTl + dst, 128, row0, col0, gma, q);
    __syncthreads();
  }
}

// ---- gchain ----
__global__ __launch_bounds__(512,1) void k_gchain(const ushort_t* PpH, const ushort_t* PpL,
                                                  const ushort_t* PTh, const ushort_t* PTl,
                                                  ushort_t* GTh, ushort_t* GTl){
  __shared__ ushort_t Ah[128*SP], Al[128*SP], Bh[128*SP], Bl[128*SP];
  int t = blockIdx.x;
  int tid = threadIdx.x;
  int w = tid >> 6, lane = tid & 63, gma = lane & 15, q = lane >> 4;
  int row0 = 32*(w >> 1), col0 = 64*(w & 1);
  size_t gslot = (size_t)t * 16384;
  if (t == 0){
    for (int i = tid*4; i < 16384; i += 2048){
      int r = i >> 7, k = i & 127;
      ushort4 zz; zz.x = zz.y = zz.z = zz.w = 0;
      *(ushort4*)&GTl[gslot + i] = zz;
      ushort4 oh;
      oh.x = (r == (k+0)) ? (ushort_t)0x3F80 : (ushort_t)0;
      oh.y = (r == (k+1)) ? (ushort_t)0x3F80 : (ushort_t)0;
      oh.z = (r == (k+2)) ? (ushort_t)0x3F80 : (ushort_t)0;
      oh.w = (r == (k+3)) ? (ushort_t)0x3F80 : (ushort_t)0;
      *(ushort4*)&GTh[gslot + i] = oh;
    }
    return;
  }
  int b0 = __ffs(t) - 1;
  int rem = t & ~(1 << b0);
  if (rem == 0){
    size_t ps = (size_t)b0 * 16384;
    for (int i = tid*4; i < 16384; i += 2048){
      *(ushort4*)&GTh[gslot + i] = *(const ushort4*)&PTh[ps + i];
      *(ushort4*)&GTl[gslot + i] = *(const ushort4*)&PTl[ps + i];
    }
    return;
  }
  lds_load_mat<512>(Ah, PpH + (size_t)b0*16384, tid);
  lds_load_mat<512>(Al, PpL + (size_t)b0*16384, tid);
  while (rem){
    int k = __ffs(rem) - 1;
    rem &= ~(1 << k);
    lds_load_mat<512>(Bh, PTh + (size_t)k*16384, tid);
    lds_load_mat<512>(Bl, PTl + (size_t)k*16384, tid);
    __syncthreads();
    float4v acc[8];
    #pragma unroll
    for (int i = 0; i < 8; i++) acc[i] = (float4v){0.f,0.f,0.f,0.f};
    if (rem){
      gemm_t<2,4,true,true>(Bh, Bl, Ah, Al, acc, row0, col0, gma, q);
      __syncthreads();
      emit_split_t<2,4>(acc, Ah, Al, SP, row0, col0, gma, q);
      __syncthreads();
    } else {
      gemm_t<2,4,true,true>(Ah, Al, Bh, Bl, acc, row0, col0, gma, q);
      emit_split_t<2,4>(acc, GTh + gslot, GTl + gslot, 128, row0, col0, gma, q);
    }
  }
}

// ---- precompMW ----
__global__ __launch_bounds__(256,1) void k_precompMW(const ushort_t* GTh, const ushort_t* GTl,
                                                     const ushort_t* UxTh, const ushort_t* UxTl,
                                                     const float* Vr, const float* Vi,
                                                     ushort_t* Mh, ushort_t* Wh){
  __shared__ ushort_t Bh[128*SP], Bl[128*SP], Ah[128*SP], Al[128*SP];
  int blk = blockIdx.x;
  int tid = threadIdx.x;
  int w = tid >> 6, lane = tid & 63, gma = lane & 15, q = lane >> 4;
  int row0 = 64*(w >> 1), col0 = 64*(w & 1);
  if (blk < 60){
    int t = blk;
    lds_load_mat<256>(Bh, GTh + (size_t)t*16384, tid);
    lds_load_mat<256>(Bl, GTl + (size_t)t*16384, tid);
    lds_load_mat<256>(Ah, UxTh, tid);
    lds_load_mat<256>(Al, UxTl, tid);
    __syncthreads();
    float4v acc[16];
    #pragma unroll
    for (int i = 0; i < 16; i++) acc[i] = (float4v){0.f,0.f,0.f,0.f};
    gemm_t<4,4,true,true>(Ah, Al, Bh, Bl, acc, row0, col0, gma, q);
    __syncthreads();
    emit_split_t<4,4>(acc, Ah, Al, SP, row0, col0, gma, q);
    __syncthreads();
    #pragma unroll
    for (int i = 0; i < 16; i++) acc[i] = (float4v){0.f,0.f,0.f,0.f};
    gemm_t<4,4,true,true>(Bh, Bl, Ah, Al, acc, row0, col0, gma, q);
    #pragma unroll
    for (int R = 0; R < 4; R++)
      #pragma unroll
      for (int C = 0; C < 4; C++){
        int c = col0 + 16*C + gma, r0 = row0 + 16*R + 4*q;
        uint2 o;
        o.x = f2bfpk(acc[R*4+C][0], acc[R*4+C][1]);
        o.y = f2bfpk(acc[R*4+C][2], acc[R*4+C][3]);
        *(uint2*)&Mh[(size_t)t*16384 + c*128 + r0] = o;
      }
  } else {
    int bx = blk - 60;
    int t = bx >> 1, which = bx & 1;
    lds_load_mat<256>(Ah, GTh + (size_t)t*16384, tid);
    lds_load_mat<256>(Al, GTl + (size_t)t*16384, tid);
    const float* V = which ? Vi : Vr;
    for (int i = tid; i < 16384; i += 256){
      int r = i >> 7, k = i & 127;
      ushort_t h, l; split2(V[i], h, l);
      Bh[r*SP + k] = h; Bl[r*SP + k] = l;
    }
    __syncthreads();
    float4v acc[16];
    #pragma unroll
    for (int i = 0; i < 16; i++) acc[i] = (float4v){0.f,0.f,0.f,0.f};
    gemm_t<4,4,true,true>(Ah, Al, Bh, Bl, acc, row0, col0, gma, q);
    #pragma unroll
    for (int R = 0; R < 4; R++)
      #pragma unroll
      for (int C = 0; C < 4; C++){
        int c = col0 + 16*C + gma, r0 = row0 + 16*R + 4*q;
        uint2 o;
        o.x = f2bfpk(acc[R*4+C][0], acc[R*4+C][1]);
        o.y = f2bfpk(acc[R*4+C][2], acc[R*4+C][3]);
        *(uint2*)&Wh[(size_t)bx*16384 + c*128 + r0] = o;
      }
  }
}

// ---- prep (fused qtrans) ----
__global__ __launch_bounds__(128) void k_prep(
    const float* x0, const float* x1, const float* x2, const float* smask,
    const float* Wp0, const float* bp0, const float* Wp1, const float* bp1,
    const float* Wp2, const float* bp2, const float* freq, const float* phem,
    const float* Ux, float* Q, float* Wgt)
{
  __shared__ float xs[768+74+35];
  __shared__ float red[DD];
  __shared__ float nrm3[3];
  __shared__ float ps[6][DD];
  int bt = blockIdx.x; int t = bt % DT;
  int d = threadIdx.x;
  const float* r0 = x0 + (size_t)bt*768;
  for (int k = d; k < 768; k += DD) xs[k] = r0[k];
  const float* r1 = x1 + (size_t)bt*74;
  if (d < 74) xs[768+d] = r1[d];
  const float* r2 = x2 + (size_t)bt*35;
  if (d < 35) xs[768+74+d] = r2[d];
  __syncthreads();
  float rep[3];
  { float acc = bp0[d]; for (int k = 0; k < 768; k++) acc += xs[k]*Wp0[k*DD+d]; rep[0] = fmaxf(acc, 0.f); }
  { float acc = bp1[d]; for (int k = 0; k < 74; k++) acc += xs[768+k]*Wp1[k*DD+d]; rep[1] = fmaxf(acc, 0.f); }
  { float acc = bp2[d]; for (int k = 0; k < 35; k++) acc += xs[768+74+k]*Wp2[k*DD+d]; rep[2] = fmaxf(acc, 0.f); }
  for (int m = 0; m < 3; m++){
    red[d] = rep[m]*rep[m];
    __syncthreads();
    for (int s = 64; s > 0; s >>= 1){ if (d < s) red[d] += red[d+s]; __syncthreads(); }
    if (d == 0) nrm3[m] = sqrtf(red[0]);
    __syncthreads();
  }
  float n0 = nrm3[0], n1 = nrm3[1], n2 = nrm3[2];
  float mx = fmaxf(n0, fmaxf(n1, n2));
  float e0 = expf(n0-mx), e1 = expf(n1-mx), e2 = expf(n2-mx);
  float einv = 1.f/(e0+e1+e2);
  if (d < 3) Wgt[bt*3+d] = (d==0?e0:(d==1?e1:e2))*einv;
  float s0 = smask[bt*2], s1 = smask[bt*2+1];
  int id = (s1 > s0) ? 1 : 0;
  float ph = (float)t * freq[id*DD+d] + phem[id*DD+d];
  float cp = cosf(ph), sp = sinf(ph);
  for (int m = 0; m < 3; m++){
    float a = rep[m] / fmaxf(nrm3[m], 1e-12f);
    ps[m][d]   = a*cp;
    ps[3+m][d] = a*sp;
  }
  __syncthreads();
  float qv[6] = {0.f,0.f,0.f,0.f,0.f,0.f};
  const float* uxr = Ux + (size_t)d*DD;
  for (int p = 0; p < DD; p++){
    float u = uxr[p];
    #pragma unroll
    for (int j = 0; j < 6; j++) qv[j] += u * ps[j][p];
  }
  #pragma unroll
  for (int j = 0; j < 6; j++)
    Q[((size_t)(j*BT) + bt)*DD + d] = qv[j];
}

// ---- vtrans: per t, A'[j,b] = G_t^T q_{j,b} for all 192 vectors ----
__global__ __launch_bounds__(512,1) void k_vtrans(const ushort_t* GTh, const float* Q, ushort_t* At){
  __shared__ ushort_t Ah[128*SP];
  __shared__ ushort_t Bs[192*SP];
  int t = blockIdx.x;
  int tid = threadIdx.x;
  int w = tid >> 6, lane = tid & 63, gma = lane & 15, q = lane >> 4;
  int row0 = (w & 3)*32, col0 = (w >> 2)*96;
  lds_load_mat<512>(Ah, GTh + (size_t)t*16384, tid);
  for (int i = tid*4; i < 192*128; i += 2048){
    int m = i >> 7, k = i & 127;
    int j = m >> 5, b = m & 31;
    const float* src = &Q[((size_t)(j*BT) + b*DT + t)*DD + k];
    uint2 o; o.x = f2bfpk(src[0], src[1]); o.y = f2bfpk(src[2], src[3]);
    *(uint2*)&Bs[m*SP + k] = o;
  }
  __syncthreads();
  float4v acc[12];
  #pragma unroll
  for (int i = 0; i < 12; i++) acc[i] = (float4v){0.f,0.f,0.f,0.f};
  gemm_t<2,6,false,false>(Ah, Ah, Bs, Bs, acc, row0, col0, gma, q);
  emit_t<2,6>(acc, At + (size_t)t*24576, 128, row0, col0, gma, q);
}

// ---- zbuild: fused rank-6 Y build + lambda-prefix; writes Z into S ----
__global__ __launch_bounds__(256) void k_zbuild(ushort_t* S, const ushort_t* At,
                                                const float* Wgt, const float* lamp){
  __shared__ ushort_t As[6*DD];
  __shared__ float wl[3];
  int blk = blockIdx.x;            // 512 = 32 b x 16 slabs
  int b = blk >> 4, slab = blk & 15;
  int tid = threadIdx.x;
  int r = slab*8 + (tid >> 5);
  int c0 = (tid & 31)*4;
  float lam = lamp[0];
  float z0=0.f, z1=0.f, z2=0.f, z3=0.f;
  size_t off = (size_t)slab*1024 + tid*4;
  for (int t = 0; t < DT; t++){
    __syncthreads();
    if (tid < 192){
      int i = tid*4;
      int jj = i >> 7, n = i & 127;
      *(ushort4*)&As[i] = *(const ushort4*)&At[(size_t)t*24576 + (jj*32 + b)*128 + n];
    }
    if (tid < 3) wl[tid] = Wgt[(b*DT + t)*3 + tid];
    __syncthreads();
    float ar[6];
    #pragma unroll
    for (int jj = 0; jj < 6; jj++) ar[jj] = bf2f(As[jj*128 + r]);
    float cb[6];
    cb[0] = wl[0]*(ar[0]+ar[3]); cb[1] = wl[1]*(ar[1]+ar[4]); cb[2] = wl[2]*(ar[2]+ar[5]);
    cb[3] = wl[0]*(ar[3]-ar[0]); cb[4] = wl[1]*(ar[4]-ar[1]); cb[5] = wl[2]*(ar[5]-ar[2]);
    float y0=0.f, y1=0.f, y2=0.f, y3=0.f;
    #pragma unroll
    for (int jj = 0; jj < 6; jj++){
      ushort4 a4 = *(const ushort4*)&As[jj*128 + c0];
      float w_ = cb[jj];
      y0 += w_*bf2f(a4.x); y1 += w_*bf2f(a4.y);
      y2 += w_*bf2f(a4.z); y3 += w_*bf2f(a4.w);
    }
    z0 = lam*z0 + y0; z1 = lam*z1 + y1;
    z2 = lam*z2 + y2; z3 = lam*z3 + y3;
    uint2 o; o.x = f2bfpk(z0, z1); o.y = f2bfpk(z2, z3);
    *(uint2*)&S[((size_t)(t*32 + b))*16384 + off] = o;
  }
}

// ---- conjmid (512 thr, per (t,b)): S <- (1-l) M S M^T + c_t I ----
__global__ __launch_bounds__(512,4) void k_conjmid(ushort_t* S, const ushort_t* Mh,
                                                   const float* lamp){
  __shared__ ushort_t Bh[128*SP], Zs[128*SP];
  int blk = blockIdx.x;
  int t = blk >> 5;
  size_t slot = (size_t)blk * 16384;
  int tid = threadIdx.x;
  int w = tid >> 6, lane = tid & 63, gma = lane & 15, q = lane >> 4;
  int row0 = 32*(w >> 1), col0 = 64*(w & 1);
  lds_load_mat2<512>(Zs, S + slot, Bh, Mh + (size_t)t*16384, tid);
  __syncthreads();
  float lam = lamp[0];
  float oml = 1.f - lam;
  float ct = powf(lam, (float)(t+1)) / 128.f;
  float4v acc[8];
  #pragma unroll
  for (int i = 0; i < 8; i++) acc[i] = (float4v){0.f,0.f,0.f,0.f};
  gemm_t<2,4,false,false>(Zs, Zs, Bh, Bh, acc, row0, col0, gma, q);
  __syncthreads();
  emit_t<2,4>(acc, Zs, SP, row0, col0, gma, q);
  __syncthreads();
  #pragma unroll
  for (int i = 0; i < 8; i++) acc[i] = (float4v){0.f,0.f,0.f,0.f};
  gemm_t<2,4,false,false>(Zs, Zs, Bh, Bh, acc, row0, col0, gma, q);
  __syncthreads();
  #pragma unroll
  for (int R = 0; R < 2; R++)
    #pragma unroll
    for (int C = 0; C < 4; C++){
      int c = col0 + 16*C + gma, r0 = row0 + 16*R + 4*q;
      float v0 = oml*acc[R*4+C][0] + ((c == r0+0) ? ct : 0.f);
      float v1 = oml*acc[R*4+C][1] + ((c == r0+1) ? ct : 0.f);
      float v2 = oml*acc[R*4+C][2] + ((c == r0+2) ? ct : 0.f);
      float v3 = oml*acc[R*4+C][3] + ((c == r0+3) ? ct : 0.f);
      uint2 o; o.x = f2bfpk(v0, v1); o.y = f2bfpk(v2, v3);
      *(uint2*)&Zs[(size_t)c*SP + r0] = o;
    }
  __syncthreads();
  lds_store_mat<512>(S + slot, Zs, tid);
}

// ---- prefix: Z_t = lam*Z_{t-1} + Y_t (32 chains), depth-4 prefetch ----
__device__ __forceinline__ void prefix_phase(ushort8_t& buf, bool doload,
                                             const ushort_t* Snext, ushort_t* Scur,
                                             float* a, float lam){
  ushort8_t u = buf;
  if (doload) buf = *(const ushort8_t*)Snext;
  #pragma unroll
  for (int i = 0; i < 8; i++) a[i] = lam*a[i] + bf2f(u[i]);
  uint4 o;
  o.x = f2bfpk(a[0],a[1]); o.y = f2bfpk(a[2],a[3]);
  o.z = f2bfpk(a[4],a[5]); o.w = f2bfpk(a[6],a[7]);
  *(uint4*)Scur = o;
}
__global__ __launch_bounds__(128) void k_prefix(ushort_t* S, const float* lamp){
  int blk = blockIdx.x;            // 512 = 32 chains x 16 slabs
  int chain = blk >> 4, slab = blk & 15;
  int tid = threadIdx.x;
  size_t off = (size_t)slab*1024 + tid*8;
  float lam = lamp[0];
  float a[8];
  #pragma unroll
  for (int i = 0; i < 8; i++) a[i] = 0.f;
  size_t addr = (size_t)chain*16384 + off;
  const size_t step = (size_t)32*16384;
  ushort8_t b0 = *(const ushort8_t*)&S[addr];
  ushort8_t b1 = *(const ushort8_t*)&S[addr + step];
  ushort8_t b2 = *(const ushort8_t*)&S[addr + 2*step];
  ushort8_t b3 = *(const ushort8_t*)&S[addr + 3*step];
  for (int t = 0; t < DT; t += 4){
    prefix_phase(b0, t+4 < DT, &S[addr + 4*step], &S[addr], a, lam); addr += step;
    prefix_phase(b1, t+5 < DT, &S[addr + 4*step], &S[addr], a, lam); addr += step;
    prefix_phase(b2, t+6 < DT, &S[addr + 4*step], &S[addr], a, lam); addr += step;
    prefix_phase(b3, t+7 < DT, &S[addr + 4*step], &S[addr], a, lam); addr += step;
  }
}

// ---- meas v4 (512 thr, per (tb,h)): staged Vs+Cs (issue-early, 16B bursts),
// single MFMA stage, VALU stage-2 diag on fp32 acc + shfl reduce.
// D[a][m] = sum_n V[a,n]*C[m,n]; p_k = sum_m D[k][m]*(vr+vi) + D[64+k][m]*(vi-vr)
__global__ __launch_bounds__(512,2) void k_meas(const ushort_t* S, const ushort_t* Wh,
                                                const float* lamp, float* Probs){
  __shared__ ushort_t Vs[128*SP], Cs[128*SP];
  __shared__ float Pd[64];
  int raw = blockIdx.x;
  // XCD-pair swizzle: raw and raw+8 are the (h=0,h=1) pair of the same tb.
  int tb = (raw & 7) | ((raw >> 4) << 3);
  int h  = (raw >> 3) & 1;
  int t = tb >> 5;
  int tid = threadIdx.x;
  int w = tid >> 6, lane = tid & 63, gma = lane & 15, q = lane >> 4;
  int row0 = 16*(w >> 1);          // a-tile base: halves at row0 and row0+64
  int col0 = 64*(w & 1);           // m base
  size_t slot = (size_t)tb * 16384;
  size_t wbase = (size_t)(t*2) * 16384;
  // issue-early: C loads (HBM) first, then V loads (L2-hot); all 16B.
  ushort8_t creg[4], vreg[4];
  #pragma unroll
  for (int c = 0; c < 4; c++)
    creg[c] = *(const ushort8_t*)&S[slot + tid*8 + c*4096];
  #pragma unroll
  for (int c = 0; c < 4; c++){
    int i = tid*8 + c*4096;
    int r = i >> 7, k = i & 127;
    size_t gsrc = wbase + ((r < 64) ? 0 : 16384) + (size_t)(64*h + (r & 63))*128 + k;
    vreg[c] = *(const ushort8_t*)&Wh[gsrc];
  }
  if (tid < 64) Pd[tid] = 0.f;
  #pragma unroll
  for (int c = 0; c < 4; c++){
    int i = tid*8 + c*4096;
    int r = i >> 7, k = i & 127;
    *(ushort8_t*)&Cs[r*SP + k] = creg[c];
  }
  #pragma unroll
  for (int c = 0; c < 4; c++){
    int i = tid*8 + c*4096;
    int r = i >> 7, k = i & 127;
    *(ushort8_t*)&Vs[r*SP + k] = vreg[c];
  }
  __syncthreads();
  float4v acc[8];
  #pragma unroll
  for (int i = 0; i < 8; i++) acc[i] = (float4v){0.f,0.f,0.f,0.f};
  #pragma unroll
  for (int ks = 0; ks < 4; ks++){
    int ko = ks*32 + q*8;
    bf16x8 aF0 = *(const bf16x8*)&Vs[(row0 + gma)*SP + ko];
    bf16x8 aF1 = *(const bf16x8*)&Vs[(row0 + 64 + gma)*SP + ko];
    bf16x8 bF[4];
    #pragma unroll
    for (int C = 0; C < 4; C++)
      bF[C] = *(const bf16x8*)&Cs[(col0 + 16*C + gma)*SP + ko];
    #pragma unroll
    for (int C = 0; C < 4; C++){
      acc[C]   = __builtin_amdgcn_mfma_f32_16x16x32_bf16(aF0, bF[C], acc[C],   0, 0, 0);
      acc[4+C] = __builtin_amdgcn_mfma_f32_16x16x32_bf16(aF1, bF[C], acc[4+C], 0, 0, 0);
    }
  }
  // stage 2: k = row0 + 4q + j; sum this lane's 4 m per C, reduce over gma.
  #pragma unroll
  for (int j = 0; j < 4; j++){
    int kr = row0 + 4*q + j;
    float s = 0.f;
    #pragma unroll
    for (int C = 0; C < 4; C++){
      int m = col0 + 16*C + gma;
      float w0 = bf2f(Vs[kr*SP + m]);          // vr_k[m]
      float w1 = bf2f(Vs[(kr + 64)*SP + m]);   // vi_k[m]
      s += acc[C][j]*(w0 + w1) + acc[4+C][j]*(w1 - w0);
    }
    #pragma unroll
    for (int off = 1; off < 16; off <<= 1)
      s += __shfl_xor(s, off, 64);
    if (gma == 0) atomicAdd(&Pd[kr], s);
  }
  __syncthreads();
  if (tid < 64){
    float lam = lamp[0];
    float ct = powf(lam, (float)(t+1)) / 128.f;
    Probs[(size_t)tb*DD + 64*h + tid] = (1.f - lam)*Pd[tid] + ct;
  }
}

// ---- head ----
__global__ __launch_bounds__(64) void k_head(const float* Probs, const float* W1, const float* b1,
                        const float* W2, const float* b2, float* out)
{
  __shared__ float ps[DD];
  __shared__ float hid[64];
  __shared__ float ov[4];
  int tb = blockIdx.x;
  int tid = threadIdx.x;
  ps[tid] = Probs[(size_t)tb*DD + tid];
  ps[tid+64] = Probs[(size_t)tb*DD + 64 + tid];
  __syncthreads();
  float acc = b1[tid];
  for (int dd = 0; dd < DD; dd++) acc += ps[dd]*W1[dd*64 + tid];
  hid[tid] = fmaxf(acc, 0.f);
  __syncthreads();
  if (tid < 4){
    float o = b2[tid];
    for (int j = 0; j < 64; j++) o += hid[j]*W2[j*4 + tid];
    ov[tid] = tanhf(o);
  }
  __syncthreads();
  if (tid == 0){
    float m = fmaxf(fmaxf(ov[0],ov[1]), fmaxf(ov[2],ov[3]));
    float lse = logf(expf(ov[0]-m)+expf(ov[1]-m)+expf(ov[2]-m)+expf(ov[3]-m));
    int t = tb >> 5, b = tb & 31;
    float* o = out + ((size_t)(b*DT + t))*4;
    o[0] = ov[0]-m-lse; o[1] = ov[1]-m-lse;
    o[2] = ov[2]-m-lse; o[3] = ov[3]-m-lse;
  }
}

extern "C" void kernel_launch(void* const* d_in, const int* in_sizes, int n_in,
                              void* d_out, int out_size, void* d_ws, size_t ws_size,
                              hipStream_t stream)
{
  const float* x0    = (const float*)d_in[0];
  const float* x1    = (const float*)d_in[1];
  const float* x2    = (const float*)d_in[2];
  const float* smask = (const float*)d_in[3];
  const float* Wp0   = (const float*)d_in[4];
  const float* bp0   = (const float*)d_in[5];
  const float* Wp1   = (const float*)d_in[6];
  const float* bp1   = (const float*)d_in[7];
  const float* Wp2   = (const float*)d_in[8];
  const float* bp2   = (const float*)d_in[9];
  const float* freq  = (const float*)d_in[10];
  const float* phem  = (const float*)d_in[11];
  const float* Ux    = (const float*)d_in[12];
  const float* Uh    = (const float*)d_in[13];
  const float* lamp  = (const float*)d_in[14];
  const float* kr    = (const float*)d_in[15];
  const float* ki    = (const float*)d_in[16];
  const float* W1    = (const float*)d_in[17];
  const float* b1    = (const float*)d_in[18];
  const float* W2    = (const float*)d_in[19];
  const float* b2    = (const float*)d_in[20];

  char* ws = (char*)d_ws;
  auto alignup = [](size_t x){ return (x + 255) & ~(size_t)255; };
  size_t off = 0;
  ushort_t* S   = (ushort_t*)(ws + off); off = alignup(off + (size_t)1920*16384*sizeof(ushort_t));
  float* Qbuf   = (float*)(ws + off);    off = alignup(off + (size_t)6*BT*DD*sizeof(float));
  float* Wgt    = (float*)(ws + off);    off = alignup(off + (size_t)BT*3*sizeof(float));
  float* Vr     = (float*)(ws + off);    off = alignup(off + (size_t)DD*DD*sizeof(float));
  float* Vi     = (float*)(ws + off);    off = alignup(off + (size_t)DD*DD*sizeof(float));
  ushort_t* UxTh = (ushort_t*)(ws + off); off = alignup(off + (size_t)DD*DD*sizeof(ushort_t));
  ushort_t* UxTl = (ushort_t*)(ws + off); off = alignup(off + (size_t)DD*DD*sizeof(ushort_t));
  float* Probs  = (float*)(ws + off);    off = alignup(off + (size_t)BT*DD*sizeof(float));
  ushort_t* PpH = (ushort_t*)(ws + off); off = alignup(off + (size_t)6*16384*sizeof(ushort_t));
  ushort_t* PpL = (ushort_t*)(ws + off); off = alignup(off + (size_t)6*16384*sizeof(ushort_t));
  ushort_t* PTh = (ushort_t*)(ws + off); off = alignup(off + (size_t)6*16384*sizeof(ushort_t));
  ushort_t* PTl = (ushort_t*)(ws + off); off = alignup(off + (size_t)6*16384*sizeof(ushort_t));
  ushort_t* Mh  = (ushort_t*)(ws + off); off = alignup(off + (size_t)60*16384*sizeof(ushort_t));
  ushort_t* Wmh = (ushort_t*)(ws + off); off = alignup(off + (size_t)120*16384*sizeof(ushort_t));
  ushort_t* GTh = (ushort_t*)(ws + off); off = alignup(off + (size_t)60*16384*sizeof(ushort_t));
  ushort_t* GTl = (ushort_t*)(ws + off); off = alignup(off + (size_t)60*16384*sizeof(ushort_t));
  ushort_t* At  = (ushort_t*)(ws + off); off = alignup(off + (size_t)60*24576*sizeof(ushort_t));
  (void)ws_size; (void)in_sizes; (void)n_in; (void)out_size;

  k_small<<<384, 128, 0, stream>>>(Ux, Uh, kr, ki, UxTh, UxTl, Vr, Vi, PpH, PpL, PTh, PTl);
  k_prep<<<BT, 128, 0, stream>>>(x0, x1, x2, smask, Wp0, bp0, Wp1, bp1, Wp2, bp2, freq, phem, Ux, Qbuf, Wgt);
  k_pow2all<<<1, 512, 0, stream>>>(PpH, PpL, PTh, PTl);
  k_gchain<<<60, 512, 0, stream>>>(PpH, PpL, PTh, PTl, GTh, GTl);
  k_precompMW<<<180, 256, 0, stream>>>(GTh, GTl, UxTh, UxTl, Vr, Vi, Mh, Wmh);
  k_vtrans<<<60, 512, 0, stream>>>(GTh, Qbuf, At);
  k_zbuild<<<512, 256, 0, stream>>>(S, At, Wgt, lamp);
  k_conjmid<<<1920, 512, 0, stream>>>(S, Mh, lamp);
  k_prefix<<<512, 128, 0, stream>>>(S, lamp);
  k_meas<<<3840, 512, 0, stream>>>(S, Wmh, lamp, Probs);
  k_head<<<BT, 64, 0, stream>>>(Probs, W1, b1, W2, b2, (float*)d_out);
}

// Round 4
// 351.874 us; speedup vs baseline: 1.2099x; 1.1100x over previous
//
#include <hip/hip_runtime.h>

// QMN B=32,T=60,D=128. Round 15: de-serialize the pow2 chain.
//  - k_pow2all (1 block, 77.5us, MfmaUtil 0.06% -- whole GPU idle) replaced by
//    5 launches of k_pow2v2: 16 blocks x 256 thr, block = (which, 16-col slice).
//    Full-A + B-slice staged in 78KB LDS; 24 MFMA/wave; bit-identical emit.
// Everything else = r14 (k_meas v4, depth-4 prefix, issue-early conjmid).

#define DB 32
#define DT 60
#define DD 128
#define BT (DB*DT)
#define SP 136

typedef unsigned short ushort_t;
typedef __attribute__((ext_vector_type(8))) __bf16 bf16x8;
typedef __attribute__((ext_vector_type(8))) unsigned short ushort8_t;
typedef __attribute__((ext_vector_type(4))) float  float4v;

__device__ __forceinline__ float bf2f(ushort_t u){
  union { unsigned int i; float f; } x; x.i = ((unsigned int)u) << 16; return x.f;
}
__device__ __forceinline__ ushort_t f2bf(float f){
  union { float f; unsigned int i; } x; x.f = f;
  unsigned int lsb = (x.i >> 16) & 1u;
  return (ushort_t)((x.i + 0x7FFFu + lsb) >> 16);
}
__device__ __forceinline__ unsigned int f2bfpk(float a, float b){
#if defined(__gfx950__) && __has_builtin(__builtin_amdgcn_cvt_pk_bf16_f32)
  auto v = __builtin_amdgcn_cvt_pk_bf16_f32(a, b);
  unsigned int r; __builtin_memcpy(&r, &v, 4); return r;
#else
  return (unsigned int)f2bf(a) | ((unsigned int)f2bf(b) << 16);
#endif
}
__device__ __forceinline__ void split2(float v, ushort_t& h, ushort_t& l){
  h = f2bf(v); l = f2bf(v - bf2f(h));
}

// D[m][n] = sum_k A[m][k]*B[n][k]
template<int RT, int CT, bool ALO, bool BLO>
__device__ __forceinline__ void gemm_t(const ushort_t* Ah, const ushort_t* Al,
                                       const ushort_t* Bh, const ushort_t* Bl,
                                       float4v* acc, int row0, int col0, int gma, int q)
{
  for (int ks = 0; ks < 4; ks++){
    int ko = ks*32 + q*8;
    bf16x8 aF[RT], aL[RT], bF[CT], bL[CT];
    #pragma unroll
    for (int R = 0; R < RT; R++){
      int row = row0 + 16*R + gma;
      aF[R] = *(const bf16x8*)&Ah[row*SP + ko];
      if (ALO) aL[R] = *(const bf16x8*)&Al[row*SP + ko];
    }
    #pragma unroll
    for (int C = 0; C < CT; C++){
      int row = col0 + 16*C + gma;
      bF[C] = *(const bf16x8*)&Bh[row*SP + ko];
      if (BLO) bL[C] = *(const bf16x8*)&Bl[row*SP + ko];
    }
    #pragma unroll
    for (int R = 0; R < RT; R++)
      #pragma unroll
      for (int C = 0; C < CT; C++){
        float4v c = acc[R*CT+C];
        c = __builtin_amdgcn_mfma_f32_16x16x32_bf16(aF[R], bF[C], c, 0, 0, 0);
        if (BLO) c = __builtin_amdgcn_mfma_f32_16x16x32_bf16(aF[R], bL[C], c, 0, 0, 0);
        if (ALO) c = __builtin_amdgcn_mfma_f32_16x16x32_bf16(aL[R], bF[C], c, 0, 0, 0);
        acc[R*CT+C] = c;
      }
  }
}

// transposed store computed(m,n) -> dst[n*stride + m]
template<int RT, int CT>
__device__ __forceinline__ void emit_t(const float4v* acc, ushort_t* dst, int stride,
                                       int row0, int col0, int gma, int q){
  #pragma unroll
  for (int R = 0; R < RT; R++)
    #pragma unroll
    for (int C = 0; C < CT; C++){
      int c = col0 + 16*C + gma, r0 = row0 + 16*R + 4*q;
      uint2 o;
      o.x = f2bfpk(acc[R*CT+C][0], acc[R*CT+C][1]);
      o.y = f2bfpk(acc[R*CT+C][2], acc[R*CT+C][3]);
      *(uint2*)&dst[(size_t)c*stride + r0] = o;
    }
}
template<int RT, int CT>
__device__ __forceinline__ void emit_split_t(const float4v* acc, ushort_t* dh, ushort_t* dl, int stride,
                                             int row0, int col0, int gma, int q){
  #pragma unroll
  for (int R = 0; R < RT; R++)
    #pragma unroll
    for (int C = 0; C < CT; C++){
      int c = col0 + 16*C + gma, r0 = row0 + 16*R + 4*q;
      ushort4 hh, ll;
      split2(acc[R*CT+C][0], hh.x, ll.x); split2(acc[R*CT+C][1], hh.y, ll.y);
      split2(acc[R*CT+C][2], hh.z, ll.z); split2(acc[R*CT+C][3], hh.w, ll.w);
      *(ushort4*)&dh[(size_t)c*stride + r0] = hh;
      *(ushort4*)&dl[(size_t)c*stride + r0] = ll;
    }
}
template<int NT>
__device__ __forceinline__ void lds_load_mat(ushort_t* dst, const ushort_t* src, int tid){
  for (int i = tid*8; i < 16384; i += NT*8){
    int r = i >> 7, k = i & 127;
    *(ushort8_t*)&dst[r*SP + k] = *(const ushort8_t*)&src[i];
  }
}
// 16 rows x 128 cols, contiguous source (2048 elems); NT=256 -> one 16B op/thr
template<int NT>
__device__ __forceinline__ void lds_load_rows16(ushort_t* dst, const ushort_t* src, int tid){
  for (int i = tid*8; i < 2048; i += NT*8){
    int r = i >> 7, k = i & 127;
    *(ushort8_t*)&dst[r*SP + k] = *(const ushort8_t*)&src[i];
  }
}
// issue-early pair stager: all global loads issued, then all ds_writes
template<int NT>
__device__ __forceinline__ void lds_load_mat2(ushort_t* d0, const ushort_t* s0,
                                              ushort_t* d1, const ushort_t* s1, int tid){
  constexpr int CH = 16384/(NT*8);
  ushort8_t r0[CH], r1[CH];
  #pragma unroll
  for (int c = 0; c < CH; c++) r0[c] = *(const ushort8_t*)&s0[tid*8 + c*NT*8];
  #pragma unroll
  for (int c = 0; c < CH; c++) r1[c] = *(const ushort8_t*)&s1[tid*8 + c*NT*8];
  #pragma unroll
  for (int c = 0; c < CH; c++){
    int i = tid*8 + c*NT*8; int r = i >> 7, k = i & 127;
    *(ushort8_t*)&d0[r*SP + k] = r0[c];
  }
  #pragma unroll
  for (int c = 0; c < CH; c++){
    int i = tid*8 + c*NT*8; int r = i >> 7, k = i & 127;
    *(ushort8_t*)&d1[r*SP + k] = r1[c];
  }
}
template<int NT>
__device__ __forceinline__ void lds_store_mat(ushort_t* dst, const ushort_t* src, int tid){
  for (int i = tid*8; i < 16384; i += NT*8){
    int r = i >> 7, k = i & 127;
    *(ushort8_t*)&dst[i] = *(const ushort8_t*)&src[r*SP + k];
  }
}

// ---- small: prepU | normv | initG ----
__global__ void k_small(const float* Ux, const float* Uh, const float* kr, const float* ki,
                        ushort_t* UxTh, ushort_t* UxTl, float* Vr, float* Vi,
                        ushort_t* PpH, ushort_t* PpL, ushort_t* PTh, ushort_t* PTl){
  int blk = blockIdx.x, d = threadIdx.x;
  if (blk < 128){
    int i = blk;
    float v = Ux[i*DD + d];
    ushort_t h, l; split2(v, h, l);
    UxTh[d*DD + i] = h; UxTl[d*DD + i] = l;
  } else if (blk < 256){
    __shared__ float red[DD];
    int k = blk - 128;
    float r = kr[k*DD+d], im = ki[k*DD+d];
    red[d] = r*r + im*im;
    __syncthreads();
    for (int s = 64; s > 0; s >>= 1){ if (d < s) red[d] += red[d+s]; __syncthreads(); }
    float nrm = fmaxf(sqrtf(red[0]), 1e-12f);
    Vr[k*DD+d] = r/nrm; Vi[k*DD+d] = im/nrm;
  } else {
    int i = blk - 256;
    float v = Uh[i*DD + d];
    ushort_t h, l; split2(v, h, l);
    PpH[i*DD + d] = h;  PpL[i*DD + d] = l;
    PTh[d*DD + i] = h;  PTl[d*DD + i] = l;
  }
}

// ---- pow2v2: one squaring step, 16 blocks (which x 8 col-slices) ----
// which==0: Pp_s = gemm(A=PT_{s-1}, B=Pp_{s-1}); which==1: PT_s = gemm(A=Pp, B=PT)
__global__ __launch_bounds__(256,2) void k_pow2v2(ushort_t* PpH, ushort_t* PpL,
                                                  ushort_t* PTh, ushort_t* PTl, int s){
  __shared__ ushort_t Ah[128*SP], Al[128*SP], Bh[16*SP], Bl[16*SP];
  int blk = blockIdx.x;
  int which = blk >> 3, sl = blk & 7;
  size_t src = (size_t)(s-1)*16384, dst = (size_t)s*16384;
  int tid = threadIdx.x;
  int w = tid >> 6, lane = tid & 63, gma = lane & 15, q = lane >> 4;
  int row0 = 32*w;
  int gcol0 = sl*16;
  const ushort_t *A_h, *A_l, *B_h, *B_l; ushort_t *D_h, *D_l;
  if (which == 0){ A_h = PTh+src; A_l = PTl+src; B_h = PpH+src; B_l = PpL+src;
                   D_h = PpH+dst; D_l = PpL+dst; }
  else           { A_h = PpH+src; A_l = PpL+src; B_h = PTh+src; B_l = PTl+src;
                   D_h = PTh+dst; D_l = PTl+dst; }
  lds_load_mat<256>(Ah, A_h, tid);
  lds_load_mat<256>(Al, A_l, tid);
  lds_load_rows16<256>(Bh, B_h + (size_t)gcol0*128, tid);
  lds_load_rows16<256>(Bl, B_l + (size_t)gcol0*128, tid);
  __syncthreads();
  float4v acc[2];
  acc[0] = (float4v){0.f,0.f,0.f,0.f};
  acc[1] = (float4v){0.f,0.f,0.f,0.f};
  gemm_t<2,1,true,true>(Ah, Al, Bh, Bl, acc, row0, 0, gma, q);
  emit_split_t<2,1>(acc, D_h, D_l, 128, row0, gcol0, gma, q);
}

// ---- gchain ----
__global__ __launch_bounds__(512,1) void k_gchain(const ushort_t* PpH, const ushort_t* PpL,
                                                  const ushort_t* PTh, const ushort_t* PTl,
                                                  ushort_t* GTh, ushort_t* GTl){
  __shared__ ushort_t Ah[128*SP], Al[128*SP], Bh[128*SP], Bl[128*SP];
  int t = blockIdx.x;
  int tid = threadIdx.x;
  int w = tid >> 6, lane = tid & 63, gma = lane & 15, q = lane >> 4;
  int row0 = 32*(w >> 1), col0 = 64*(w & 1);
  size_t gslot = (size_t)t * 16384;
  if (t == 0){
    for (int i = tid*4; i < 16384; i += 2048){
      int r = i >> 7, k = i & 127;
      ushort4 zz; zz.x = zz.y = zz.z = zz.w = 0;
      *(ushort4*)&GTl[gslot + i] = zz;
      ushort4 oh;
      oh.x = (r == (k+0)) ? (ushort_t)0x3F80 : (ushort_t)0;
      oh.y = (r == (k+1)) ? (ushort_t)0x3F80 : (ushort_t)0;
      oh.z = (r == (k+2)) ? (ushort_t)0x3F80 : (ushort_t)0;
      oh.w = (r == (k+3)) ? (ushort_t)0x3F80 : (ushort_t)0;
      *(ushort4*)&GTh[gslot + i] = oh;
    }
    return;
  }
  int b0 = __ffs(t) - 1;
  int rem = t & ~(1 << b0);
  if (rem == 0){
    size_t ps = (size_t)b0 * 16384;
    for (int i = tid*4; i < 16384; i += 2048){
      *(ushort4*)&GTh[gslot + i] = *(const ushort4*)&PTh[ps + i];
      *(ushort4*)&GTl[gslot + i] = *(const ushort4*)&PTl[ps + i];
    }
    return;
  }
  lds_load_mat<512>(Ah, PpH + (size_t)b0*16384, tid);
  lds_load_mat<512>(Al, PpL + (size_t)b0*16384, tid);
  while (rem){
    int k = __ffs(rem) - 1;
    rem &= ~(1 << k);
    lds_load_mat<512>(Bh, PTh + (size_t)k*16384, tid);
    lds_load_mat<512>(Bl, PTl + (size_t)k*16384, tid);
    __syncthreads();
    float4v acc[8];
    #pragma unroll
    for (int i = 0; i < 8; i++) acc[i] = (float4v){0.f,0.f,0.f,0.f};
    if (rem){
      gemm_t<2,4,true,true>(Bh, Bl, Ah, Al, acc, row0, col0, gma, q);
      __syncthreads();
      emit_split_t<2,4>(acc, Ah, Al, SP, row0, col0, gma, q);
      __syncthreads();
    } else {
      gemm_t<2,4,true,true>(Ah, Al, Bh, Bl, acc, row0, col0, gma, q);
      emit_split_t<2,4>(acc, GTh + gslot, GTl + gslot, 128, row0, col0, gma, q);
    }
  }
}

// ---- precompMW ----
__global__ __launch_bounds__(256,1) void k_precompMW(const ushort_t* GTh, const ushort_t* GTl,
                                                     const ushort_t* UxTh, const ushort_t* UxTl,
                                                     const float* Vr, const float* Vi,
                                                     ushort_t* Mh, ushort_t* Wh){
  __shared__ ushort_t Bh[128*SP], Bl[128*SP], Ah[128*SP], Al[128*SP];
  int blk = blockIdx.x;
  int tid = threadIdx.x;
  int w = tid >> 6, lane = tid & 63, gma = lane & 15, q = lane >> 4;
  int row0 = 64*(w >> 1), col0 = 64*(w & 1);
  if (blk < 60){
    int t = blk;
    lds_load_mat<256>(Bh, GTh + (size_t)t*16384, tid);
    lds_load_mat<256>(Bl, GTl + (size_t)t*16384, tid);
    lds_load_mat<256>(Ah, UxTh, tid);
    lds_load_mat<256>(Al, UxTl, tid);
    __syncthreads();
    float4v acc[16];
    #pragma unroll
    for (int i = 0; i < 16; i++) acc[i] = (float4v){0.f,0.f,0.f,0.f};
    gemm_t<4,4,true,true>(Ah, Al, Bh, Bl, acc, row0, col0, gma, q);
    __syncthreads();
    emit_split_t<4,4>(acc, Ah, Al, SP, row0, col0, gma, q);
    __syncthreads();
    #pragma unroll
    for (int i = 0; i < 16; i++) acc[i] = (float4v){0.f,0.f,0.f,0.f};
    gemm_t<4,4,true,true>(Bh, Bl, Ah, Al, acc, row0, col0, gma, q);
    #pragma unroll
    for (int R = 0; R < 4; R++)
      #pragma unroll
      for (int C = 0; C < 4; C++){
        int c = col0 + 16*C + gma, r0 = row0 + 16*R + 4*q;
        uint2 o;
        o.x = f2bfpk(acc[R*4+C][0], acc[R*4+C][1]);
        o.y = f2bfpk(acc[R*4+C][2], acc[R*4+C][3]);
        *(uint2*)&Mh[(size_t)t*16384 + c*128 + r0] = o;
      }
  } else {
    int bx = blk - 60;
    int t = bx >> 1, which = bx & 1;
    lds_load_mat<256>(Ah, GTh + (size_t)t*16384, tid);
    lds_load_mat<256>(Al, GTl + (size_t)t*16384, tid);
    const float* V = which ? Vi : Vr;
    for (int i = tid; i < 16384; i += 256){
      int r = i >> 7, k = i & 127;
      ushort_t h, l; split2(V[i], h, l);
      Bh[r*SP + k] = h; Bl[r*SP + k] = l;
    }
    __syncthreads();
    float4v acc[16];
    #pragma unroll
    for (int i = 0; i < 16; i++) acc[i] = (float4v){0.f,0.f,0.f,0.f};
    gemm_t<4,4,true,true>(Ah, Al, Bh, Bl, acc, row0, col0, gma, q);
    #pragma unroll
    for (int R = 0; R < 4; R++)
      #pragma unroll
      for (int C = 0; C < 4; C++){
        int c = col0 + 16*C + gma, r0 = row0 + 16*R + 4*q;
        uint2 o;
        o.x = f2bfpk(acc[R*4+C][0], acc[R*4+C][1]);
        o.y = f2bfpk(acc[R*4+C][2], acc[R*4+C][3]);
        *(uint2*)&Wh[(size_t)bx*16384 + c*128 + r0] = o;
      }
  }
}

// ---- prep (fused qtrans) ----
__global__ __launch_bounds__(128) void k_prep(
    const float* x0, const float* x1, const float* x2, const float* smask,
    const float* Wp0, const float* bp0, const float* Wp1, const float* bp1,
    const float* Wp2, const float* bp2, const float* freq, const float* phem,
    const float* Ux, float* Q, float* Wgt)
{
  __shared__ float xs[768+74+35];
  __shared__ float red[DD];
  __shared__ float nrm3[3];
  __shared__ float ps[6][DD];
  int bt = blockIdx.x; int t = bt % DT;
  int d = threadIdx.x;
  const float* r0 = x0 + (size_t)bt*768;
  for (int k = d; k < 768; k += DD) xs[k] = r0[k];
  const float* r1 = x1 + (size_t)bt*74;
  if (d < 74) xs[768+d] = r1[d];
  const float* r2 = x2 + (size_t)bt*35;
  if (d < 35) xs[768+74+d] = r2[d];
  __syncthreads();
  float rep[3];
  { float acc = bp0[d]; for (int k = 0; k < 768; k++) acc += xs[k]*Wp0[k*DD+d]; rep[0] = fmaxf(acc, 0.f); }
  { float acc = bp1[d]; for (int k = 0; k < 74; k++) acc += xs[768+k]*Wp1[k*DD+d]; rep[1] = fmaxf(acc, 0.f); }
  { float acc = bp2[d]; for (int k = 0; k < 35; k++) acc += xs[768+74+k]*Wp2[k*DD+d]; rep[2] = fmaxf(acc, 0.f); }
  for (int m = 0; m < 3; m++){
    red[d] = rep[m]*rep[m];
    __syncthreads();
    for (int s = 64; s > 0; s >>= 1){ if (d < s) red[d] += red[d+s]; __syncthreads(); }
    if (d == 0) nrm3[m] = sqrtf(red[0]);
    __syncthreads();
  }
  float n0 = nrm3[0], n1 = nrm3[1], n2 = nrm3[2];
  float mx = fmaxf(n0, fmaxf(n1, n2));
  float e0 = expf(n0-mx), e1 = expf(n1-mx), e2 = expf(n2-mx);
  float einv = 1.f/(e0+e1+e2);
  if (d < 3) Wgt[bt*3+d] = (d==0?e0:(d==1?e1:e2))*einv;
  float s0 = smask[bt*2], s1 = smask[bt*2+1];
  int id = (s1 > s0) ? 1 : 0;
  float ph = (float)t * freq[id*DD+d] + phem[id*DD+d];
  float cp = cosf(ph), sp = sinf(ph);
  for (int m = 0; m < 3; m++){
    float a = rep[m] / fmaxf(nrm3[m], 1e-12f);
    ps[m][d]   = a*cp;
    ps[3+m][d] = a*sp;
  }
  __syncthreads();
  float qv[6] = {0.f,0.f,0.f,0.f,0.f,0.f};
  const float* uxr = Ux + (size_t)d*DD;
  for (int p = 0; p < DD; p++){
    float u = uxr[p];
    #pragma unroll
    for (int j = 0; j < 6; j++) qv[j] += u * ps[j][p];
  }
  #pragma unroll
  for (int j = 0; j < 6; j++)
    Q[((size_t)(j*BT) + bt)*DD + d] = qv[j];
}

// ---- vtrans: per t, A'[j,b] = G_t^T q_{j,b} for all 192 vectors ----
__global__ __launch_bounds__(512,1) void k_vtrans(const ushort_t* GTh, const float* Q, ushort_t* At){
  __shared__ ushort_t Ah[128*SP];
  __shared__ ushort_t Bs[192*SP];
  int t = blockIdx.x;
  int tid = threadIdx.x;
  int w = tid >> 6, lane = tid & 63, gma = lane & 15, q = lane >> 4;
  int row0 = (w & 3)*32, col0 = (w >> 2)*96;
  lds_load_mat<512>(Ah, GTh + (size_t)t*16384, tid);
  for (int i = tid*4; i < 192*128; i += 2048){
    int m = i >> 7, k = i & 127;
    int j = m >> 5, b = m & 31;
    const float* src = &Q[((size_t)(j*BT) + b*DT + t)*DD + k];
    uint2 o; o.x = f2bfpk(src[0], src[1]); o.y = f2bfpk(src[2], src[3]);
    *(uint2*)&Bs[m*SP + k] = o;
  }
  __syncthreads();
  float4v acc[12];
  #pragma unroll
  for (int i = 0; i < 12; i++) acc[i] = (float4v){0.f,0.f,0.f,0.f};
  gemm_t<2,6,false,false>(Ah, Ah, Bs, Bs, acc, row0, col0, gma, q);
  emit_t<2,6>(acc, At + (size_t)t*24576, 128, row0, col0, gma, q);
}

// ---- zbuild: fused rank-6 Y build + lambda-prefix; writes Z into S ----
__global__ __launch_bounds__(256) void k_zbuild(ushort_t* S, const ushort_t* At,
                                                const float* Wgt, const float* lamp){
  __shared__ ushort_t As[6*DD];
  __shared__ float wl[3];
  int blk = blockIdx.x;            // 512 = 32 b x 16 slabs
  int b = blk >> 4, slab = blk & 15;
  int tid = threadIdx.x;
  int r = slab*8 + (tid >> 5);
  int c0 = (tid & 31)*4;
  float lam = lamp[0];
  float z0=0.f, z1=0.f, z2=0.f, z3=0.f;
  size_t off = (size_t)slab*1024 + tid*4;
  for (int t = 0; t < DT; t++){
    __syncthreads();
    if (tid < 192){
      int i = tid*4;
      int jj = i >> 7, n = i & 127;
      *(ushort4*)&As[i] = *(const ushort4*)&At[(size_t)t*24576 + (jj*32 + b)*128 + n];
    }
    if (tid < 3) wl[tid] = Wgt[(b*DT + t)*3 + tid];
    __syncthreads();
    float ar[6];
    #pragma unroll
    for (int jj = 0; jj < 6; jj++) ar[jj] = bf2f(As[jj*128 + r]);
    float cb[6];
    cb[0] = wl[0]*(ar[0]+ar[3]); cb[1] = wl[1]*(ar[1]+ar[4]); cb[2] = wl[2]*(ar[2]+ar[5]);
    cb[3] = wl[0]*(ar[3]-ar[0]); cb[4] = wl[1]*(ar[4]-ar[1]); cb[5] = wl[2]*(ar[5]-ar[2]);
    float y0=0.f, y1=0.f, y2=0.f, y3=0.f;
    #pragma unroll
    for (int jj = 0; jj < 6; jj++){
      ushort4 a4 = *(const ushort4*)&As[jj*128 + c0];
      float w_ = cb[jj];
      y0 += w_*bf2f(a4.x); y1 += w_*bf2f(a4.y);
      y2 += w_*bf2f(a4.z); y3 += w_*bf2f(a4.w);
    }
    z0 = lam*z0 + y0; z1 = lam*z1 + y1;
    z2 = lam*z2 + y2; z3 = lam*z3 + y3;
    uint2 o; o.x = f2bfpk(z0, z1); o.y = f2bfpk(z2, z3);
    *(uint2*)&S[((size_t)(t*32 + b))*16384 + off] = o;
  }
}

// ---- conjmid (512 thr, per (t,b)): S <- (1-l) M S M^T + c_t I ----
__global__ __launch_bounds__(512,4) void k_conjmid(ushort_t* S, const ushort_t* Mh,
                                                   const float* lamp){
  __shared__ ushort_t Bh[128*SP], Zs[128*SP];
  int blk = blockIdx.x;
  int t = blk >> 5;
  size_t slot = (size_t)blk * 16384;
  int tid = threadIdx.x;
  int w = tid >> 6, lane = tid & 63, gma = lane & 15, q = lane >> 4;
  int row0 = 32*(w >> 1), col0 = 64*(w & 1);
  lds_load_mat2<512>(Zs, S + slot, Bh, Mh + (size_t)t*16384, tid);
  __syncthreads();
  float lam = lamp[0];
  float oml = 1.f - lam;
  float ct = powf(lam, (float)(t+1)) / 128.f;
  float4v acc[8];
  #pragma unroll
  for (int i = 0; i < 8; i++) acc[i] = (float4v){0.f,0.f,0.f,0.f};
  gemm_t<2,4,false,false>(Zs, Zs, Bh, Bh, acc, row0, col0, gma, q);
  __syncthreads();
  emit_t<2,4>(acc, Zs, SP, row0, col0, gma, q);
  __syncthreads();
  #pragma unroll
  for (int i = 0; i < 8; i++) acc[i] = (float4v){0.f,0.f,0.f,0.f};
  gemm_t<2,4,false,false>(Zs, Zs, Bh, Bh, acc, row0, col0, gma, q);
  __syncthreads();
  #pragma unroll
  for (int R = 0; R < 2; R++)
    #pragma unroll
    for (int C = 0; C < 4; C++){
      int c = col0 + 16*C + gma, r0 = row0 + 16*R + 4*q;
      float v0 = oml*acc[R*4+C][0] + ((c == r0+0) ? ct : 0.f);
      float v1 = oml*acc[R*4+C][1] + ((c == r0+1) ? ct : 0.f);
      float v2 = oml*acc[R*4+C][2] + ((c == r0+2) ? ct : 0.f);
      float v3 = oml*acc[R*4+C][3] + ((c == r0+3) ? ct : 0.f);
      uint2 o; o.x = f2bfpk(v0, v1); o.y = f2bfpk(v2, v3);
      *(uint2*)&Zs[(size_t)c*SP + r0] = o;
    }
  __syncthreads();
  lds_store_mat<512>(S + slot, Zs, tid);
}

// ---- prefix: Z_t = lam*Z_{t-1} + Y_t (32 chains), depth-4 prefetch ----
__device__ __forceinline__ void prefix_phase(ushort8_t& buf, bool doload,
                                             const ushort_t* Snext, ushort_t* Scur,
                                             float* a, float lam){
  ushort8_t u = buf;
  if (doload) buf = *(const ushort8_t*)Snext;
  #pragma unroll
  for (int i = 0; i < 8; i++) a[i] = lam*a[i] + bf2f(u[i]);
  uint4 o;
  o.x = f2bfpk(a[0],a[1]); o.y = f2bfpk(a[2],a[3]);
  o.z = f2bfpk(a[4],a[5]); o.w = f2bfpk(a[6],a[7]);
  *(uint4*)Scur = o;
}
__global__ __launch_bounds__(128) void k_prefix(ushort_t* S, const float* lamp){
  int blk = blockIdx.x;            // 512 = 32 chains x 16 slabs
  int chain = blk >> 4, slab = blk & 15;
  int tid = threadIdx.x;
  size_t off = (size_t)slab*1024 + tid*8;
  float lam = lamp[0];
  float a[8];
  #pragma unroll
  for (int i = 0; i < 8; i++) a[i] = 0.f;
  size_t addr = (size_t)chain*16384 + off;
  const size_t step = (size_t)32*16384;
  ushort8_t b0 = *(const ushort8_t*)&S[addr];
  ushort8_t b1 = *(const ushort8_t*)&S[addr + step];
  ushort8_t b2 = *(const ushort8_t*)&S[addr + 2*step];
  ushort8_t b3 = *(const ushort8_t*)&S[addr + 3*step];
  for (int t = 0; t < DT; t += 4){
    prefix_phase(b0, t+4 < DT, &S[addr + 4*step], &S[addr], a, lam); addr += step;
    prefix_phase(b1, t+5 < DT, &S[addr + 4*step], &S[addr], a, lam); addr += step;
    prefix_phase(b2, t+6 < DT, &S[addr + 4*step], &S[addr], a, lam); addr += step;
    prefix_phase(b3, t+7 < DT, &S[addr + 4*step], &S[addr], a, lam); addr += step;
  }
}

// ---- meas v4 (512 thr, per (tb,h)): staged Vs+Cs (issue-early, 16B bursts),
// single MFMA stage, VALU stage-2 diag on fp32 acc + shfl reduce.
// D[a][m] = sum_n V[a,n]*C[m,n]; p_k = sum_m D[k][m]*(vr+vi) + D[64+k][m]*(vi-vr)
__global__ __launch_bounds__(512,2) void k_meas(const ushort_t* S, const ushort_t* Wh,
                                                const float* lamp, float* Probs){
  __shared__ ushort_t Vs[128*SP], Cs[128*SP];
  __shared__ float Pd[64];
  int raw = blockIdx.x;
  // XCD-pair swizzle: raw and raw+8 are the (h=0,h=1) pair of the same tb.
  int tb = (raw & 7) | ((raw >> 4) << 3);
  int h  = (raw >> 3) & 1;
  int t = tb >> 5;
  int tid = threadIdx.x;
  int w = tid >> 6, lane = tid & 63, gma = lane & 15, q = lane >> 4;
  int row0 = 16*(w >> 1);          // a-tile base: halves at row0 and row0+64
  int col0 = 64*(w & 1);           // m base
  size_t slot = (size_t)tb * 16384;
  size_t wbase = (size_t)(t*2) * 16384;
  // issue-early: C loads (HBM) first, then V loads (L2-hot); all 16B.
  ushort8_t creg[4], vreg[4];
  #pragma unroll
  for (int c = 0; c < 4; c++)
    creg[c] = *(const ushort8_t*)&S[slot + tid*8 + c*4096];
  #pragma unroll
  for (int c = 0; c < 4; c++){
    int i = tid*8 + c*4096;
    int r = i >> 7, k = i & 127;
    size_t gsrc = wbase + ((r < 64) ? 0 : 16384) + (size_t)(64*h + (r & 63))*128 + k;
    vreg[c] = *(const ushort8_t*)&Wh[gsrc];
  }
  if (tid < 64) Pd[tid] = 0.f;
  #pragma unroll
  for (int c = 0; c < 4; c++){
    int i = tid*8 + c*4096;
    int r = i >> 7, k = i & 127;
    *(ushort8_t*)&Cs[r*SP + k] = creg[c];
  }
  #pragma unroll
  for (int c = 0; c < 4; c++){
    int i = tid*8 + c*4096;
    int r = i >> 7, k = i & 127;
    *(ushort8_t*)&Vs[r*SP + k] = vreg[c];
  }
  __syncthreads();
  float4v acc[8];
  #pragma unroll
  for (int i = 0; i < 8; i++) acc[i] = (float4v){0.f,0.f,0.f,0.f};
  #pragma unroll
  for (int ks = 0; ks < 4; ks++){
    int ko = ks*32 + q*8;
    bf16x8 aF0 = *(const bf16x8*)&Vs[(row0 + gma)*SP + ko];
    bf16x8 aF1 = *(const bf16x8*)&Vs[(row0 + 64 + gma)*SP + ko];
    bf16x8 bF[4];
    #pragma unroll
    for (int C = 0; C < 4; C++)
      bF[C] = *(const bf16x8*)&Cs[(col0 + 16*C + gma)*SP + ko];
    #pragma unroll
    for (int C = 0; C < 4; C++){
      acc[C]   = __builtin_amdgcn_mfma_f32_16x16x32_bf16(aF0, bF[C], acc[C],   0, 0, 0);
      acc[4+C] = __builtin_amdgcn_mfma_f32_16x16x32_bf16(aF1, bF[C], acc[4+C], 0, 0, 0);
    }
  }
  // stage 2: k = row0 + 4q + j; sum this lane's 4 m per C, reduce over gma.
  #pragma unroll
  for (int j = 0; j < 4; j++){
    int kr = row0 + 4*q + j;
    float s = 0.f;
    #pragma unroll
    for (int C = 0; C < 4; C++){
      int m = col0 + 16*C + gma;
      float w0 = bf2f(Vs[kr*SP + m]);          // vr_k[m]
      float w1 = bf2f(Vs[(kr + 64)*SP + m]);   // vi_k[m]
      s += acc[C][j]*(w0 + w1) + acc[4+C][j]*(w1 - w0);
    }
    #pragma unroll
    for (int off = 1; off < 16; off <<= 1)
      s += __shfl_xor(s, off, 64);
    if (gma == 0) atomicAdd(&Pd[kr], s);
  }
  __syncthreads();
  if (tid < 64){
    float lam = lamp[0];
    float ct = powf(lam, (float)(t+1)) / 128.f;
    Probs[(size_t)tb*DD + 64*h + tid] = (1.f - lam)*Pd[tid] + ct;
  }
}

// ---- head ----
__global__ __launch_bounds__(64) void k_head(const float* Probs, const float* W1, const float* b1,
                        const float* W2, const float* b2, float* out)
{
  __shared__ float ps[DD];
  __shared__ float hid[64];
  __shared__ float ov[4];
  int tb = blockIdx.x;
  int tid = threadIdx.x;
  ps[tid] = Probs[(size_t)tb*DD + tid];
  ps[tid+64] = Probs[(size_t)tb*DD + 64 + tid];
  __syncthreads();
  float acc = b1[tid];
  for (int dd = 0; dd < DD; dd++) acc += ps[dd]*W1[dd*64 + tid];
  hid[tid] = fmaxf(acc, 0.f);
  __syncthreads();
  if (tid < 4){
    float o = b2[tid];
    for (int j = 0; j < 64; j++) o += hid[j]*W2[j*4 + tid];
    ov[tid] = tanhf(o);
  }
  __syncthreads();
  if (tid == 0){
    float m = fmaxf(fmaxf(ov[0],ov[1]), fmaxf(ov[2],ov[3]));
    float lse = logf(expf(ov[0]-m)+expf(ov[1]-m)+expf(ov[2]-m)+expf(ov[3]-m));
    int t = tb >> 5, b = tb & 31;
    float* o = out + ((size_t)(b*DT + t))*4;
    o[0] = ov[0]-m-lse; o[1] = ov[1]-m-lse;
    o[2] = ov[2]-m-lse; o[3] = ov[3]-m-lse;
  }
}

extern "C" void kernel_launch(void* const* d_in, const int* in_sizes, int n_in,
                              void* d_out, int out_size, void* d_ws, size_t ws_size,
                              hipStream_t stream)
{
  const float* x0    = (const float*)d_in[0];
  const float* x1    = (const float*)d_in[1];
  const float* x2    = (const float*)d_in[2];
  const float* smask = (const float*)d_in[3];
  const float* Wp0   = (const float*)d_in[4];
  const float* bp0   = (const float*)d_in[5];
  const float* Wp1   = (const float*)d_in[6];
  const float* bp1   = (const float*)d_in[7];
  const float* Wp2   = (const float*)d_in[8];
  const float* bp2   = (const float*)d_in[9];
  const float* freq  = (const float*)d_in[10];
  const float* phem  = (const float*)d_in[11];
  const float* Ux    = (const float*)d_in[12];
  const float* Uh    = (const float*)d_in[13];
  const float* lamp  = (const float*)d_in[14];
  const float* kr    = (const float*)d_in[15];
  const float* ki    = (const float*)d_in[16];
  const float* W1    = (const float*)d_in[17];
  const float* b1    = (const float*)d_in[18];
  const float* W2    = (const float*)d_in[19];
  const float* b2    = (const float*)d_in[20];

  char* ws = (char*)d_ws;
  auto alignup = [](size_t x){ return (x + 255) & ~(size_t)255; };
  size_t off = 0;
  ushort_t* S   = (ushort_t*)(ws + off); off = alignup(off + (size_t)1920*16384*sizeof(ushort_t));
  float* Qbuf   = (float*)(ws + off);    off = alignup(off + (size_t)6*BT*DD*sizeof(float));
  float* Wgt    = (float*)(ws + off);    off = alignup(off + (size_t)BT*3*sizeof(float));
  float* Vr     = (float*)(ws + off);    off = alignup(off + (size_t)DD*DD*sizeof(float));
  float* Vi     = (float*)(ws + off);    off = alignup(off + (size_t)DD*DD*sizeof(float));
  ushort_t* UxTh = (ushort_t*)(ws + off); off = alignup(off + (size_t)DD*DD*sizeof(ushort_t));
  ushort_t* UxTl = (ushort_t*)(ws + off); off = alignup(off + (size_t)DD*DD*sizeof(ushort_t));
  float* Probs  = (float*)(ws + off);    off = alignup(off + (size_t)BT*DD*sizeof(float));
  ushort_t* PpH = (ushort_t*)(ws + off); off = alignup(off + (size_t)6*16384*sizeof(ushort_t));
  ushort_t* PpL = (ushort_t*)(ws + off); off = alignup(off + (size_t)6*16384*sizeof(ushort_t));
  ushort_t* PTh = (ushort_t*)(ws + off); off = alignup(off + (size_t)6*16384*sizeof(ushort_t));
  ushort_t* PTl = (ushort_t*)(ws + off); off = alignup(off + (size_t)6*16384*sizeof(ushort_t));
  ushort_t* Mh  = (ushort_t*)(ws + off); off = alignup(off + (size_t)60*16384*sizeof(ushort_t));
  ushort_t* Wmh = (ushort_t*)(ws + off); off = alignup(off + (size_t)120*16384*sizeof(ushort_t));
  ushort_t* GTh = (ushort_t*)(ws + off); off = alignup(off + (size_t)60*16384*sizeof(ushort_t));
  ushort_t* GTl = (ushort_t*)(ws + off); off = alignup(off + (size_t)60*16384*sizeof(ushort_t));
  ushort_t* At  = (ushort_t*)(ws + off); off = alignup(off + (size_t)60*24576*sizeof(ushort_t));
  (void)ws_size; (void)in_sizes; (void)n_in; (void)out_size;

  k_small<<<384, 128, 0, stream>>>(Ux, Uh, kr, ki, UxTh, UxTl, Vr, Vi, PpH, PpL, PTh, PTl);
  k_prep<<<BT, 128, 0, stream>>>(x0, x1, x2, smask, Wp0, bp0, Wp1, bp1, Wp2, bp2, freq, phem, Ux, Qbuf, Wgt);
  for (int s = 1; s <= 5; s++)
    k_pow2v2<<<16, 256, 0, stream>>>(PpH, PpL, PTh, PTl, s);
  k_gchain<<<60, 512, 0, stream>>>(PpH, PpL, PTh, PTl, GTh, GTl);
  k_precompMW<<<180, 256, 0, stream>>>(GTh, GTl, UxTh, UxTl, Vr, Vi, Mh, Wmh);
  k_vtrans<<<60, 512, 0, stream>>>(GTh, Qbuf, At);
  k_zbuild<<<512, 256, 0, stream>>>(S, At, Wgt, lamp);
  k_conjmid<<<1920, 512, 0, stream>>>(S, Mh, lamp);
  k_prefix<<<512, 128, 0, stream>>>(S, lamp);
  k_meas<<<3840, 512, 0, stream>>>(S, Wmh, lamp, Probs);
  k_head<<<BT, 64, 0, stream>>>(Probs, W1, b1, W2, b2, (float*)d_out);
}